// Round 1
// baseline (1365.189 us; speedup 1.0000x reference)
//
#include <hip/hip_runtime.h>
#include <cstddef>

#define TT 64  // timesteps, innermost contiguous dim everywhere

// ---------------- CUBA LIF scan over 64 in-register z values ----------------
// c = 0.7*c + z; v = 0.75*v + c; s = (v>=1); v = s ? 0 : v
// (1.0f-0.3f == 0.7f and 1.0f-0.25f == 0.75f exactly in fp32, matching jax)
__device__ __forceinline__ void cuba_scan(float* zz) {
    float c = 0.f, v = 0.f;
#pragma unroll
    for (int t = 0; t < TT; t++) {
        c = 0.7f * c + zz[t];
        v = 0.75f * v + c;
        float s = (v >= 1.0f) ? 1.0f : 0.0f;
        v = (v >= 1.0f) ? 0.0f : v;
        zz[t] = s;
    }
}

// ---------------- weight_norm: w = g * v / ||v||  (norm per output channel) --
// one block per output channel o; K = fan_in. TR=true stores transposed (K,O).
template <bool TR>
__global__ __launch_bounds__(256) void wnorm(const float* __restrict__ v,
                                             const float* __restrict__ g,
                                             float* __restrict__ w, int O, int K) {
    __shared__ float red[256];
    const int o = blockIdx.x;
    float s = 0.f;
    for (int k = threadIdx.x; k < K; k += 256) {
        float x = v[(size_t)o * K + k];
        s += x * x;
    }
    red[threadIdx.x] = s;
    __syncthreads();
    for (int off = 128; off > 0; off >>= 1) {
        if (threadIdx.x < off) red[threadIdx.x] += red[threadIdx.x + off];
        __syncthreads();
    }
    const float scale = g[o] / sqrtf(red[0]);
    for (int k = threadIdx.x; k < K; k += 256) {
        float val = scale * v[(size_t)o * K + k];
        if (TR) w[(size_t)k * O + o] = val;
        else    w[(size_t)o * K + k] = val;
    }
}

// ---------------- fused conv(5x5, stride 4, pad 1) + CUBA ----------------
// Thread = one output neuron (b,o,oy,ox); accumulates z[64] in registers via
// float4 time-vector loads, then runs the LIF scan and writes 64 spikes.
// Block = all CO channels x (256/CO) spatial positions -> input pixels are
// shared CO-ways within the block (L1/L2 hits).
template <int CI, int HI, int WI, int CO, int HO, int WO>
__global__ __launch_bounds__(256) void conv_cuba(const float* __restrict__ x,
                                                 const float* __restrict__ w,
                                                 float* __restrict__ sout) {
    constexpr int OPB = CO;
    constexpr int SPB = 256 / OPB;
    const int b = blockIdx.y;
    const int o = threadIdx.x % OPB;
    const int spi = blockIdx.x * SPB + threadIdx.x / OPB;
    const int ox = spi % WO, oy = spi / WO;

    float zz[TT];
#pragma unroll
    for (int t = 0; t < TT; t++) zz[t] = 0.f;

    const float* xb = x + (size_t)b * CI * HI * WI * TT;
    const float* wb = w + (size_t)o * CI * 25;

    for (int ci = 0; ci < CI; ci++) {
#pragma unroll
        for (int ky = 0; ky < 5; ky++) {
            const int iy = oy * 4 + ky - 1;
            if (iy < 0 || iy >= HI) continue;
#pragma unroll
            for (int kx = 0; kx < 5; kx++) {
                const int ix = ox * 4 + kx - 1;
                if (ix < 0 || ix >= WI) continue;
                const float wv = wb[(ci * 5 + ky) * 5 + kx];
                const float4* xp =
                    (const float4*)(xb + ((size_t)(ci * HI + iy) * WI + ix) * TT);
#pragma unroll
                for (int j = 0; j < TT / 4; j++) {
                    float4 xv = xp[j];
                    zz[4 * j + 0] += wv * xv.x;
                    zz[4 * j + 1] += wv * xv.y;
                    zz[4 * j + 2] += wv * xv.z;
                    zz[4 * j + 3] += wv * xv.w;
                }
            }
        }
    }
    cuba_scan(zz);
    float4* op = (float4*)(sout + (((size_t)b * CO + o) * (HO * WO) + spi) * TT);
#pragma unroll
    for (int j = 0; j < TT / 4; j++)
        op[j] = make_float4(zz[4 * j], zz[4 * j + 1], zz[4 * j + 2], zz[4 * j + 3]);
}

// ---------------- dense1 (256 -> 2056) + CUBA ----------------
// Stage the whole (256,64) activation block of one batch in LDS (64 KB).
// Weights pre-transposed (I,O) so the per-i weight load is coalesced over o.
__global__ __launch_bounds__(256) void dense1_cuba(const float* __restrict__ sin,
                                                   const float* __restrict__ wT,
                                                   float* __restrict__ sout) {
    __shared__ float lds[256 * TT];  // 64 KB
    const int b = blockIdx.y;
    const float4* src = (const float4*)(sin + (size_t)b * 256 * TT);
    float4* ldsv = (float4*)lds;
    for (int idx = threadIdx.x; idx < 256 * TT / 4; idx += 256) ldsv[idx] = src[idx];
    __syncthreads();

    const int o = blockIdx.x * 256 + threadIdx.x;
    const int oc = (o < 2056) ? o : 2055;  // clamp: inactive threads stay in-bounds
    float zz[TT];
#pragma unroll
    for (int t = 0; t < TT; t++) zz[t] = 0.f;

#pragma unroll 2
    for (int i = 0; i < 256; i++) {
        const float wv = wT[(size_t)i * 2056 + oc];
        const float4* sp = (const float4*)(lds + i * TT);
#pragma unroll
        for (int j = 0; j < TT / 4; j++) {
            float4 sv = sp[j];
            zz[4 * j + 0] += wv * sv.x;
            zz[4 * j + 1] += wv * sv.y;
            zz[4 * j + 2] += wv * sv.z;
            zz[4 * j + 3] += wv * sv.w;
        }
    }
    if (o < 2056) {
        cuba_scan(zz);
        float4* op = (float4*)(sout + ((size_t)b * 2056 + o) * TT);
#pragma unroll
        for (int j = 0; j < TT / 4; j++)
            op[j] = make_float4(zz[4 * j], zz[4 * j + 1], zz[4 * j + 2], zz[4 * j + 3]);
    }
}

// ---------------- dense2 (2056 -> 11): z only, t-parallel ----------------
// block = (o,b); 256 threads = 4 i-groups x 64 t. Coalesced over t.
__global__ __launch_bounds__(256) void dense2_z(const float* __restrict__ s4,
                                                const float* __restrict__ w,
                                                float* __restrict__ z4) {
    const int o = blockIdx.x, b = blockIdx.y;
    const int t = threadIdx.x & 63, grp = threadIdx.x >> 6;
    const float* src = s4 + (size_t)b * 2056 * TT;
    const float* wp = w + (size_t)o * 2056;
    float acc = 0.f;
    for (int i = grp; i < 2056; i += 4) acc += wp[i] * src[(size_t)i * TT + t];
    __shared__ float red[256];
    red[threadIdx.x] = acc;
    __syncthreads();
    if (threadIdx.x < 64) {
        float z = red[threadIdx.x] + red[threadIdx.x + 64] + red[threadIdx.x + 128] +
                  red[threadIdx.x + 192];
        z4[((size_t)b * 11 + o) * TT + threadIdx.x] = z;
    }
}

// ---------------- final CUBA over dense2 output (176 neurons) ----------------
__global__ __launch_bounds__(256) void cuba_out(const float* __restrict__ z4,
                                                float* __restrict__ out) {
    const int idx = threadIdx.x;
    if (idx < 176) {
        float zz[TT];
#pragma unroll
        for (int t = 0; t < TT; t++) zz[t] = z4[(size_t)idx * TT + t];
        cuba_scan(zz);
#pragma unroll
        for (int t = 0; t < TT; t++) out[(size_t)idx * TT + t] = zz[t];
    }
}

extern "C" void kernel_launch(void* const* d_in, const int* in_sizes, int n_in,
                              void* d_out, int out_size, void* d_ws, size_t ws_size,
                              hipStream_t stream) {
    const float* x   = (const float*)d_in[0];
    const float* c1v = (const float*)d_in[1];  const float* c1g = (const float*)d_in[2];
    const float* c2v = (const float*)d_in[3];  const float* c2g = (const float*)d_in[4];
    const float* c3v = (const float*)d_in[5];  const float* c3g = (const float*)d_in[6];
    const float* d1v = (const float*)d_in[7];  const float* d1g = (const float*)d_in[8];
    const float* d2v = (const float*)d_in[9];  const float* d2g = (const float*)d_in[10];

    float* ws = (float*)d_ws;
    size_t off = 0;
    float* w1   = ws + off; off += 8 * 2 * 25;              // 400
    float* w2   = ws + off; off += 32 * 8 * 25;             // 6400
    float* w3   = ws + off; off += 64 * 32 * 25;            // 51200
    float* wd1T = ws + off; off += (size_t)256 * 2056;      // transposed (I,O)
    float* wd2  = ws + off; off += (size_t)11 * 2056;
    float* s1   = ws + off; off += (size_t)16 * 8 * 32 * 32 * TT;
    float* s2   = ws + off; off += (size_t)16 * 32 * 8 * 8 * TT;
    float* s3   = ws + off; off += (size_t)16 * 64 * 2 * 2 * TT;
    float* s4   = ws + off; off += (size_t)16 * 2056 * TT;
    float* z4   = ws + off; off += (size_t)16 * 11 * TT;
    (void)ws_size; (void)in_sizes; (void)n_in; (void)out_size;

    // normalized weights
    wnorm<false><<<dim3(8),    dim3(256), 0, stream>>>(c1v, c1g, w1, 8, 50);
    wnorm<false><<<dim3(32),   dim3(256), 0, stream>>>(c2v, c2g, w2, 32, 200);
    wnorm<false><<<dim3(64),   dim3(256), 0, stream>>>(c3v, c3g, w3, 64, 800);
    wnorm<true> <<<dim3(2056), dim3(256), 0, stream>>>(d1v, d1g, wd1T, 2056, 256);
    wnorm<false><<<dim3(11),   dim3(256), 0, stream>>>(d2v, d2g, wd2, 11, 2056);

    // fused synapse + CUBA pipeline
    conv_cuba<2, 128, 128, 8, 32, 32><<<dim3(32, 16), dim3(256), 0, stream>>>(x, w1, s1);
    conv_cuba<8, 32, 32, 32, 8, 8>   <<<dim3(8, 16),  dim3(256), 0, stream>>>(s1, w2, s2);
    conv_cuba<32, 8, 8, 64, 2, 2>    <<<dim3(1, 16),  dim3(256), 0, stream>>>(s2, w3, s3);
    dense1_cuba<<<dim3(9, 16),  dim3(256), 0, stream>>>(s3, wd1T, s4);
    dense2_z   <<<dim3(11, 16), dim3(256), 0, stream>>>(s4, wd2, z4);
    cuba_out   <<<dim3(1), dim3(256), 0, stream>>>(z4, (float*)d_out);
}

// Round 2
// 693.862 us; speedup vs baseline: 1.9675x; 1.9675x over previous
//
#include <hip/hip_runtime.h>
#include <cstddef>

#define TT 64  // timesteps, innermost contiguous dim everywhere

// ---------------- CUBA LIF step helpers (carry c,v across chunks) ----------
// c = 0.7*c + z; v = 0.75*v + c; s = (v>=1); v = s ? 0 : v
__device__ __forceinline__ void scanc(float& c, float& v, float& z) {
    c = fmaf(0.7f, c, z);
    v = fmaf(0.75f, v, c);
    float s = (v >= 1.0f) ? 1.0f : 0.0f;
    v = (v >= 1.0f) ? 0.0f : v;
    z = s;
}
__device__ __forceinline__ void scan4(float& c, float& v, float4& a) {
    scanc(c, v, a.x); scanc(c, v, a.y); scanc(c, v, a.z); scanc(c, v, a.w);
}
__device__ __forceinline__ void fma4(float4& a, float w, const float4& x) {
    a.x = fmaf(w, x.x, a.x); a.y = fmaf(w, x.y, a.y);
    a.z = fmaf(w, x.z, a.z); a.w = fmaf(w, x.w, a.w);
}

// ---------------- weight_norm: w = g * v / ||v|| (norm per output channel) --
// one block per output channel o; K = fan_in. TR=true stores transposed (K,O).
template <bool TR>
__global__ __launch_bounds__(256) void wnorm(const float* __restrict__ v,
                                             const float* __restrict__ g,
                                             float* __restrict__ w, int O, int K) {
    __shared__ float red[256];
    const int o = blockIdx.x;
    float s = 0.f;
    for (int k = threadIdx.x; k < K; k += 256) {
        float x = v[(size_t)o * K + k];
        s += x * x;
    }
    red[threadIdx.x] = s;
    __syncthreads();
    for (int off = 128; off > 0; off >>= 1) {
        if (threadIdx.x < off) red[threadIdx.x] += red[threadIdx.x + off];
        __syncthreads();
    }
    const float scale = g[o] / sqrtf(red[0]);
    for (int k = threadIdx.x; k < K; k += 256) {
        float val = scale * v[(size_t)o * K + k];
        if (TR) w[(size_t)k * O + o] = val;
        else    w[(size_t)o * K + k] = val;
    }
}

// ---------------- fused conv(5x5,s4,p1) + CUBA, time-chunked (16 t/chunk) ---
// Thread = one output neuron (b,o,oy,ox). 4 chunks of 4 float4 accumulators
// (max ~50 VGPR live) with LIF carry across chunks -> no scratch spill.
template <int CI, int HI, int WI, int CO, int HO, int WO>
__global__ __launch_bounds__(256) void conv_cuba(const float* __restrict__ x,
                                                 const float* __restrict__ w,
                                                 float* __restrict__ sout) {
    constexpr int OPB = CO;
    constexpr int SPB = 256 / OPB;
    const int b = blockIdx.y;
    const int o = threadIdx.x % OPB;
    const int spi = blockIdx.x * SPB + threadIdx.x / OPB;
    const int ox = spi % WO, oy = spi / WO;

    const float* xb = x + (size_t)b * CI * HI * WI * TT;
    const float* wb = w + (size_t)o * CI * 25;
    float4* op = (float4*)(sout + (((size_t)b * CO + o) * (HO * WO) + spi) * TT);

    float c = 0.f, v = 0.f;
    for (int tc = 0; tc < 4; tc++) {
        float4 a0 = {0, 0, 0, 0}, a1 = a0, a2 = a0, a3 = a0;
        for (int ci = 0; ci < CI; ci++) {
#pragma unroll
            for (int ky = 0; ky < 5; ky++) {
                const int iy = oy * 4 + ky - 1;
                if (iy < 0 || iy >= HI) continue;
#pragma unroll
                for (int kx = 0; kx < 5; kx++) {
                    const int ix = ox * 4 + kx - 1;
                    if (ix < 0 || ix >= WI) continue;
                    const float wv = wb[(ci * 5 + ky) * 5 + kx];
                    const float4* xp =
                        (const float4*)(xb + ((size_t)((ci * HI + iy) * WI + ix)) * TT) +
                        tc * 4;
                    float4 x0 = xp[0], x1 = xp[1], x2 = xp[2], x3 = xp[3];
                    fma4(a0, wv, x0); fma4(a1, wv, x1);
                    fma4(a2, wv, x2); fma4(a3, wv, x3);
                }
            }
        }
        scan4(c, v, a0); scan4(c, v, a1); scan4(c, v, a2); scan4(c, v, a3);
        op[tc * 4 + 0] = a0; op[tc * 4 + 1] = a1;
        op[tc * 4 + 2] = a2; op[tc * 4 + 3] = a3;
    }
}

// ---------------- conv3 z, t-parallel, 8 output channels per thread --------
// wave = 64 time lanes for one (b,spi,og); weights transposed (k,O) so the 8
// channel weights per tap are two broadcast float4 loads. 512 tasks = 128 blk.
__global__ __launch_bounds__(256) void conv3_z(const float* __restrict__ s2,
                                               const float* __restrict__ wT,
                                               float* __restrict__ z3) {
    const int t = threadIdx.x & 63;
    const int task = blockIdx.x * 4 + (threadIdx.x >> 6);  // 0..511
    const int og = task & 7;
    const int spi = (task >> 3) & 3;
    const int b = task >> 5;
    const int oy = spi >> 1, ox = spi & 1;

    float acc0 = 0, acc1 = 0, acc2 = 0, acc3 = 0, acc4 = 0, acc5 = 0, acc6 = 0, acc7 = 0;
    const float* xb = s2 + (size_t)b * 32 * 8 * 8 * TT + t;

    for (int ci = 0; ci < 32; ci++) {
#pragma unroll
        for (int ky = 0; ky < 5; ky++) {
            const int iy = oy * 4 + ky - 1;
            if (iy < 0 || iy >= 8) continue;
#pragma unroll
            for (int kx = 0; kx < 5; kx++) {
                const int ix = ox * 4 + kx - 1;
                if (ix < 0 || ix >= 8) continue;
                const float xv = xb[((size_t)((ci * 8 + iy) * 8 + ix)) * TT];
                const float4* wp =
                    (const float4*)(wT + ((ci * 25 + ky * 5 + kx)) * 64 + og * 8);
                const float4 wA = wp[0], wB = wp[1];
                acc0 = fmaf(wA.x, xv, acc0); acc1 = fmaf(wA.y, xv, acc1);
                acc2 = fmaf(wA.z, xv, acc2); acc3 = fmaf(wA.w, xv, acc3);
                acc4 = fmaf(wB.x, xv, acc4); acc5 = fmaf(wB.y, xv, acc5);
                acc6 = fmaf(wB.z, xv, acc6); acc7 = fmaf(wB.w, xv, acc7);
            }
        }
    }
    // feature index = o*4 + spi (C,H,W flatten); layout (b, feat, t)
    float* zb = z3 + ((size_t)b * 256 + (size_t)og * 32 + spi) * TT + t;
    zb[0 * 4 * TT] = acc0; zb[1 * 4 * TT] = acc1; zb[2 * 4 * TT] = acc2;
    zb[3 * 4 * TT] = acc3; zb[4 * 4 * TT] = acc4; zb[5 * 4 * TT] = acc5;
    zb[6 * 4 * TT] = acc6; zb[7 * 4 * TT] = acc7;
}

// ---------------- generic de-fused CUBA scan: z (N,64) -> spikes (N,64) -----
__global__ __launch_bounds__(256) void scan_s(const float* __restrict__ z,
                                              float* __restrict__ s, int N) {
    const int n = blockIdx.x * 256 + threadIdx.x;
    if (n >= N) return;
    const float4* zp = (const float4*)(z + (size_t)n * TT);
    float4* sp = (float4*)(s + (size_t)n * TT);
    float c = 0.f, v = 0.f;
    for (int tc = 0; tc < 4; tc++) {
        float4 a0 = zp[tc * 4 + 0], a1 = zp[tc * 4 + 1];
        float4 a2 = zp[tc * 4 + 2], a3 = zp[tc * 4 + 3];
        scan4(c, v, a0); scan4(c, v, a1); scan4(c, v, a2); scan4(c, v, a3);
        sp[tc * 4 + 0] = a0; sp[tc * 4 + 1] = a1;
        sp[tc * 4 + 2] = a2; sp[tc * 4 + 3] = a3;
    }
}

// ---------------- dense1 z (256 -> 2056), t-chunked, 4 outputs/thread -------
// Block = one (b, t-chunk); stages the 256x16 activation slice (16 KB LDS).
// Thread owns 4 consecutive o -> float4 weight load, LDS traffic / 4.
__global__ __launch_bounds__(256) void dense1_z(const float* __restrict__ s3,
                                                const float* __restrict__ wT,
                                                float* __restrict__ zd) {
    __shared__ float lds[256 * 16];
    const int tc = blockIdx.y, b = blockIdx.z;

    const float4* src = (const float4*)(s3 + ((size_t)b * 256 + threadIdx.x) * TT + tc * 16);
    float4* dst = (float4*)(lds + threadIdx.x * 16);
    dst[0] = src[0]; dst[1] = src[1]; dst[2] = src[2]; dst[3] = src[3];
    __syncthreads();

    const int o0 = (blockIdx.x * 256 + threadIdx.x) * 4;
    const bool wr = (o0 < 2056);
    const int oc = wr ? o0 : 2052;

    float4 A00 = {0,0,0,0}, A01 = A00, A02 = A00, A03 = A00;  // o+0, t quads
    float4 A10 = A00, A11 = A00, A12 = A00, A13 = A00;        // o+1
    float4 A20 = A00, A21 = A00, A22 = A00, A23 = A00;        // o+2
    float4 A30 = A00, A31 = A00, A32 = A00, A33 = A00;        // o+3

    for (int i = 0; i < 256; i++) {
        const float4 wv = *(const float4*)(wT + (size_t)i * 2056 + oc);
        const float4* ap = (const float4*)(lds + i * 16);
        const float4 a0 = ap[0], a1 = ap[1], a2 = ap[2], a3 = ap[3];
        fma4(A00, wv.x, a0); fma4(A01, wv.x, a1); fma4(A02, wv.x, a2); fma4(A03, wv.x, a3);
        fma4(A10, wv.y, a0); fma4(A11, wv.y, a1); fma4(A12, wv.y, a2); fma4(A13, wv.y, a3);
        fma4(A20, wv.z, a0); fma4(A21, wv.z, a1); fma4(A22, wv.z, a2); fma4(A23, wv.z, a3);
        fma4(A30, wv.w, a0); fma4(A31, wv.w, a1); fma4(A32, wv.w, a2); fma4(A33, wv.w, a3);
    }
    if (wr) {
        float4* o0p = (float4*)(zd + ((size_t)b * 2056 + oc + 0) * TT + tc * 16);
        float4* o1p = (float4*)(zd + ((size_t)b * 2056 + oc + 1) * TT + tc * 16);
        float4* o2p = (float4*)(zd + ((size_t)b * 2056 + oc + 2) * TT + tc * 16);
        float4* o3p = (float4*)(zd + ((size_t)b * 2056 + oc + 3) * TT + tc * 16);
        o0p[0] = A00; o0p[1] = A01; o0p[2] = A02; o0p[3] = A03;
        o1p[0] = A10; o1p[1] = A11; o1p[2] = A12; o1p[3] = A13;
        o2p[0] = A20; o2p[1] = A21; o2p[2] = A22; o2p[3] = A23;
        o3p[0] = A30; o3p[1] = A31; o3p[2] = A32; o3p[3] = A33;
    }
}

// ---------------- dense2 (2056 -> 11): z only, t-parallel ----------------
__global__ __launch_bounds__(256) void dense2_z(const float* __restrict__ s4,
                                                const float* __restrict__ w,
                                                float* __restrict__ z4) {
    const int o = blockIdx.x, b = blockIdx.y;
    const int t = threadIdx.x & 63, grp = threadIdx.x >> 6;
    const float* src = s4 + (size_t)b * 2056 * TT;
    const float* wp = w + (size_t)o * 2056;
    float acc = 0.f;
    for (int i = grp; i < 2056; i += 4) acc = fmaf(wp[i], src[(size_t)i * TT + t], acc);
    __shared__ float red[256];
    red[threadIdx.x] = acc;
    __syncthreads();
    if (threadIdx.x < 64) {
        float z = red[threadIdx.x] + red[threadIdx.x + 64] + red[threadIdx.x + 128] +
                  red[threadIdx.x + 192];
        z4[((size_t)b * 11 + o) * TT + threadIdx.x] = z;
    }
}

// ---------------- final CUBA over dense2 output (176 neurons) ----------------
__global__ __launch_bounds__(256) void cuba_out(const float* __restrict__ z4,
                                                float* __restrict__ out) {
    const int n = threadIdx.x;
    if (n < 176) {
        const float4* zp = (const float4*)(z4 + (size_t)n * TT);
        float4* sp = (float4*)(out + (size_t)n * TT);
        float c = 0.f, v = 0.f;
        for (int tc = 0; tc < 4; tc++) {
            float4 a0 = zp[tc * 4 + 0], a1 = zp[tc * 4 + 1];
            float4 a2 = zp[tc * 4 + 2], a3 = zp[tc * 4 + 3];
            scan4(c, v, a0); scan4(c, v, a1); scan4(c, v, a2); scan4(c, v, a3);
            sp[tc * 4 + 0] = a0; sp[tc * 4 + 1] = a1;
            sp[tc * 4 + 2] = a2; sp[tc * 4 + 3] = a3;
        }
    }
}

extern "C" void kernel_launch(void* const* d_in, const int* in_sizes, int n_in,
                              void* d_out, int out_size, void* d_ws, size_t ws_size,
                              hipStream_t stream) {
    const float* x   = (const float*)d_in[0];
    const float* c1v = (const float*)d_in[1];  const float* c1g = (const float*)d_in[2];
    const float* c2v = (const float*)d_in[3];  const float* c2g = (const float*)d_in[4];
    const float* c3v = (const float*)d_in[5];  const float* c3g = (const float*)d_in[6];
    const float* d1v = (const float*)d_in[7];  const float* d1g = (const float*)d_in[8];
    const float* d2v = (const float*)d_in[9];  const float* d2g = (const float*)d_in[10];

    float* ws = (float*)d_ws;
    size_t off = 0;
    float* w1   = ws + off; off += 8 * 2 * 25;              // conv1 (O,K)
    float* w2   = ws + off; off += 32 * 8 * 25;             // conv2 (O,K)
    float* w3T  = ws + off; off += 64 * 32 * 25;            // conv3 transposed (K,O)
    float* wd1T = ws + off; off += (size_t)256 * 2056;      // dense1 transposed (I,O)
    float* wd2  = ws + off; off += (size_t)11 * 2056;
    float* s1   = ws + off; off += (size_t)16 * 8 * 32 * 32 * TT;   // 8.39M floats
    float* s2   = ws + off; off += (size_t)16 * 32 * 8 * 8 * TT;
    float* s3   = ws + off; off += (size_t)16 * 256 * TT;
    float* s4   = ws + off; off += (size_t)16 * 2056 * TT;
    float* z4   = ws + off; off += (size_t)16 * 11 * TT;
    // z3 / zd1 alias the s1 region (dead after conv2 reads it; stream-ordered)
    float* z3   = s1;                       // 262144 floats
    float* zd1  = s1 + 262144;              // 2,105,344 floats (fits in s1's 8.39M)
    (void)ws_size; (void)in_sizes; (void)n_in; (void)out_size;

    // normalized weights
    wnorm<false><<<dim3(8),    dim3(256), 0, stream>>>(c1v, c1g, w1, 8, 50);
    wnorm<false><<<dim3(32),   dim3(256), 0, stream>>>(c2v, c2g, w2, 32, 200);
    wnorm<true> <<<dim3(64),   dim3(256), 0, stream>>>(c3v, c3g, w3T, 64, 800);
    wnorm<true> <<<dim3(2056), dim3(256), 0, stream>>>(d1v, d1g, wd1T, 2056, 256);
    wnorm<false><<<dim3(11),   dim3(256), 0, stream>>>(d2v, d2g, wd2, 11, 2056);

    // pipeline
    conv_cuba<2, 128, 128, 8, 32, 32><<<dim3(32, 16), dim3(256), 0, stream>>>(x, w1, s1);
    conv_cuba<8, 32, 32, 32, 8, 8>   <<<dim3(8, 16),  dim3(256), 0, stream>>>(s1, w2, s2);
    conv3_z<<<dim3(128), dim3(256), 0, stream>>>(s2, w3T, z3);
    scan_s <<<dim3(16),  dim3(256), 0, stream>>>(z3, s3, 4096);
    dense1_z<<<dim3(3, 4, 16), dim3(256), 0, stream>>>(s3, wd1T, zd1);
    scan_s <<<dim3(129), dim3(256), 0, stream>>>(zd1, s4, 32896);
    dense2_z<<<dim3(11, 16), dim3(256), 0, stream>>>(s4, wd2, z4);
    cuba_out<<<dim3(1), dim3(256), 0, stream>>>(z4, (float*)d_out);
}

// Round 3
// 521.680 us; speedup vs baseline: 2.6169x; 1.3301x over previous
//
#include <hip/hip_runtime.h>
#include <cstddef>

#define TT 64  // timesteps

// ---------------- CUBA LIF step helpers ----------------
__device__ __forceinline__ void scanc(float& c, float& v, float& z) {
    c = fmaf(0.7f, c, z);
    v = fmaf(0.75f, v, c);
    float s = (v >= 1.0f) ? 1.0f : 0.0f;
    v = (v >= 1.0f) ? 0.0f : v;
    z = s;
}
__device__ __forceinline__ void scan4(float& c, float& v, float4& a) {
    scanc(c, v, a.x); scanc(c, v, a.y); scanc(c, v, a.z); scanc(c, v, a.w);
}

// ---------------- weight_norm (per output channel); TR stores (K,O) --------
template <bool TR>
__global__ __launch_bounds__(256) void wnorm(const float* __restrict__ v,
                                             const float* __restrict__ g,
                                             float* __restrict__ w, int O, int K) {
    __shared__ float red[256];
    const int o = blockIdx.x;
    float s = 0.f;
    for (int k = threadIdx.x; k < K; k += 256) {
        float x = v[(size_t)o * K + k];
        s += x * x;
    }
    red[threadIdx.x] = s;
    __syncthreads();
    for (int off = 128; off > 0; off >>= 1) {
        if (threadIdx.x < off) red[threadIdx.x] += red[threadIdx.x + off];
        __syncthreads();
    }
    const float scale = g[o] / sqrtf(red[0]);
    for (int k = threadIdx.x; k < K; k += 256) {
        float val = scale * v[(size_t)o * K + k];
        if (TR) w[(size_t)k * O + o] = val;
        else    w[(size_t)o * K + k] = val;
    }
}

// ---------------- conv1 (2->8, 128x128 -> 32x32) fused with CUBA -----------
// Wave = one (b, oy, ox); lane = t. Coalesced 256B x-loads, broadcast weights,
// 8 accumulators. Scan via per-wave LDS transpose: lanes 0..7 each scan one
// channel in-register. No z1 buffer, no reassociation (ci->ky->kx fmaf order).
__global__ __launch_bounds__(256) void conv1_cuba(const float* __restrict__ x,
                                                  const float* __restrict__ w1T,
                                                  float* __restrict__ s1) {
    __shared__ float lds[4][8][68];  // +4 pad: conflict-free column reads
    const int wid = threadIdx.x >> 6, t = threadIdx.x & 63;
    const int task = blockIdx.x * 4 + wid;  // 0..16383
    const int spi = task & 1023, b = task >> 10;
    const int oy = spi >> 5, ox = spi & 31;

    float a0=0,a1=0,a2=0,a3=0,a4=0,a5=0,a6=0,a7=0;
    const float* xb = x + (size_t)b * 2 * 128 * 128 * TT + t;

    for (int ci = 0; ci < 2; ci++) {
#pragma unroll
        for (int ky = 0; ky < 5; ky++) {
            const int iy = oy * 4 + ky - 1;
            if (iy < 0 || iy >= 128) continue;
#pragma unroll
            for (int kx = 0; kx < 5; kx++) {
                const int ix = ox * 4 + kx - 1;
                if (ix < 0 || ix >= 128) continue;
                const float xv = xb[((size_t)((ci * 128 + iy) * 128 + ix)) * TT];
                const float4* wp = (const float4*)(w1T + (ci * 25 + ky * 5 + kx) * 8);
                const float4 wA = wp[0], wB = wp[1];
                a0 = fmaf(wA.x, xv, a0); a1 = fmaf(wA.y, xv, a1);
                a2 = fmaf(wA.z, xv, a2); a3 = fmaf(wA.w, xv, a3);
                a4 = fmaf(wB.x, xv, a4); a5 = fmaf(wB.y, xv, a5);
                a6 = fmaf(wB.z, xv, a6); a7 = fmaf(wB.w, xv, a7);
            }
        }
    }
    lds[wid][0][t] = a0; lds[wid][1][t] = a1; lds[wid][2][t] = a2; lds[wid][3][t] = a3;
    lds[wid][4][t] = a4; lds[wid][5][t] = a5; lds[wid][6][t] = a6; lds[wid][7][t] = a7;
    __syncthreads();
    if (t < 8) {
        const int ch = t;
        float4 r[16];
#pragma unroll
        for (int j = 0; j < 16; j++) r[j] = *(const float4*)&lds[wid][ch][j * 4];
        float c = 0.f, v = 0.f;
#pragma unroll
        for (int j = 0; j < 16; j++) scan4(c, v, r[j]);
        float4* op = (float4*)(s1 + (((size_t)b * 8 + ch) * 1024 + spi) * TT);
#pragma unroll
        for (int j = 0; j < 16; j++) op[j] = r[j];
    }
}

// ---------------- conv2 z (8->32, 32x32 -> 8x8), t-parallel, 16 o/wave -----
__global__ __launch_bounds__(256) void conv2_z(const float* __restrict__ s1,
                                               const float* __restrict__ w2T,
                                               float* __restrict__ z2) {
    const int wid = threadIdx.x >> 6, t = threadIdx.x & 63;
    const int task = blockIdx.x * 4 + wid;  // 0..2047
    const int og = task & 1;
    const int spi = (task >> 1) & 63;
    const int b = task >> 7;
    const int oy = spi >> 3, ox = spi & 7;

    float a[16];
#pragma unroll
    for (int j = 0; j < 16; j++) a[j] = 0.f;
    const float* xb = s1 + (size_t)b * 8 * 32 * 32 * TT + t;

    for (int ci = 0; ci < 8; ci++) {
#pragma unroll
        for (int ky = 0; ky < 5; ky++) {
            const int iy = oy * 4 + ky - 1;
            if (iy < 0 || iy >= 32) continue;
#pragma unroll
            for (int kx = 0; kx < 5; kx++) {
                const int ix = ox * 4 + kx - 1;
                if (ix < 0 || ix >= 32) continue;
                const float xv = xb[((size_t)((ci * 32 + iy) * 32 + ix)) * TT];
                const float4* wp =
                    (const float4*)(w2T + (ci * 25 + ky * 5 + kx) * 32 + og * 16);
                const float4 w0 = wp[0], w1 = wp[1], w2 = wp[2], w3 = wp[3];
                a[0]  = fmaf(w0.x, xv, a[0]);  a[1]  = fmaf(w0.y, xv, a[1]);
                a[2]  = fmaf(w0.z, xv, a[2]);  a[3]  = fmaf(w0.w, xv, a[3]);
                a[4]  = fmaf(w1.x, xv, a[4]);  a[5]  = fmaf(w1.y, xv, a[5]);
                a[6]  = fmaf(w1.z, xv, a[6]);  a[7]  = fmaf(w1.w, xv, a[7]);
                a[8]  = fmaf(w2.x, xv, a[8]);  a[9]  = fmaf(w2.y, xv, a[9]);
                a[10] = fmaf(w2.z, xv, a[10]); a[11] = fmaf(w2.w, xv, a[11]);
                a[12] = fmaf(w3.x, xv, a[12]); a[13] = fmaf(w3.y, xv, a[13]);
                a[14] = fmaf(w3.z, xv, a[14]); a[15] = fmaf(w3.w, xv, a[15]);
            }
        }
    }
    float* zb = z2 + (((size_t)b * 32 + og * 16) * 64 + spi) * TT + t;
#pragma unroll
    for (int j = 0; j < 16; j++) zb[(size_t)j * 64 * TT] = a[j];
}

// ---------------- conv3 z (32->64, 8x8 -> 2x2), t-parallel, 8 o/wave -------
// (unchanged from passing round-2 kernel: bit-identical accumulation)
__global__ __launch_bounds__(256) void conv3_z(const float* __restrict__ s2,
                                               const float* __restrict__ wT,
                                               float* __restrict__ z3) {
    const int t = threadIdx.x & 63;
    const int task = blockIdx.x * 4 + (threadIdx.x >> 6);  // 0..511
    const int og = task & 7;
    const int spi = (task >> 3) & 3;
    const int b = task >> 5;
    const int oy = spi >> 1, ox = spi & 1;

    float acc0 = 0, acc1 = 0, acc2 = 0, acc3 = 0, acc4 = 0, acc5 = 0, acc6 = 0, acc7 = 0;
    const float* xb = s2 + (size_t)b * 32 * 8 * 8 * TT + t;

    for (int ci = 0; ci < 32; ci++) {
#pragma unroll
        for (int ky = 0; ky < 5; ky++) {
            const int iy = oy * 4 + ky - 1;
            if (iy < 0 || iy >= 8) continue;
#pragma unroll
            for (int kx = 0; kx < 5; kx++) {
                const int ix = ox * 4 + kx - 1;
                if (ix < 0 || ix >= 8) continue;
                const float xv = xb[((size_t)((ci * 8 + iy) * 8 + ix)) * TT];
                const float4* wp =
                    (const float4*)(wT + ((ci * 25 + ky * 5 + kx)) * 64 + og * 8);
                const float4 wA = wp[0], wB = wp[1];
                acc0 = fmaf(wA.x, xv, acc0); acc1 = fmaf(wA.y, xv, acc1);
                acc2 = fmaf(wA.z, xv, acc2); acc3 = fmaf(wA.w, xv, acc3);
                acc4 = fmaf(wB.x, xv, acc4); acc5 = fmaf(wB.y, xv, acc5);
                acc6 = fmaf(wB.z, xv, acc6); acc7 = fmaf(wB.w, xv, acc7);
            }
        }
    }
    float* zb = z3 + ((size_t)b * 256 + (size_t)og * 32 + spi) * TT + t;
    zb[0 * 4 * TT] = acc0; zb[1 * 4 * TT] = acc1; zb[2 * 4 * TT] = acc2;
    zb[3 * 4 * TT] = acc3; zb[4 * 4 * TT] = acc4; zb[5 * 4 * TT] = acc5;
    zb[6 * 4 * TT] = acc6; zb[7 * 4 * TT] = acc7;
}

// ---------------- generic de-fused CUBA scan: z (N,64) -> spikes (N,64) -----
__global__ __launch_bounds__(256) void scan_s(const float* __restrict__ z,
                                              float* __restrict__ s, int N) {
    const int n = blockIdx.x * 256 + threadIdx.x;
    if (n >= N) return;
    const float4* zp = (const float4*)(z + (size_t)n * TT);
    float4* sp = (float4*)(s + (size_t)n * TT);
    float c = 0.f, v = 0.f;
    for (int tc = 0; tc < 4; tc++) {
        float4 a0 = zp[tc * 4 + 0], a1 = zp[tc * 4 + 1];
        float4 a2 = zp[tc * 4 + 2], a3 = zp[tc * 4 + 3];
        scan4(c, v, a0); scan4(c, v, a1); scan4(c, v, a2); scan4(c, v, a3);
        sp[tc * 4 + 0] = a0; sp[tc * 4 + 1] = a1;
        sp[tc * 4 + 2] = a2; sp[tc * 4 + 3] = a3;
    }
}

// ---------------- dense1 z (256 -> 2056), t-parallel, 16 o/wave -------------
__global__ __launch_bounds__(256) void dense1_z(const float* __restrict__ s3,
                                                const float* __restrict__ wT,
                                                float* __restrict__ zd) {
    const int wid = threadIdx.x >> 6, t = threadIdx.x & 63;
    const int task = blockIdx.x * 4 + wid;  // 0..2063
    const int b = task / 129;
    const int og = task - b * 129;
    const int o0 = og * 16;

    float a[16];
#pragma unroll
    for (int j = 0; j < 16; j++) a[j] = 0.f;
    const float* ab = s3 + (size_t)b * 256 * TT + t;

    for (int i = 0; i < 256; i++) {
        const float av = ab[(size_t)i * TT];
        const float4* wp = (const float4*)(wT + (size_t)i * 2056 + o0);
        const float4 w0 = wp[0], w1 = wp[1], w2 = wp[2], w3 = wp[3];
        a[0]  = fmaf(w0.x, av, a[0]);  a[1]  = fmaf(w0.y, av, a[1]);
        a[2]  = fmaf(w0.z, av, a[2]);  a[3]  = fmaf(w0.w, av, a[3]);
        a[4]  = fmaf(w1.x, av, a[4]);  a[5]  = fmaf(w1.y, av, a[5]);
        a[6]  = fmaf(w1.z, av, a[6]);  a[7]  = fmaf(w1.w, av, a[7]);
        a[8]  = fmaf(w2.x, av, a[8]);  a[9]  = fmaf(w2.y, av, a[9]);
        a[10] = fmaf(w2.z, av, a[10]); a[11] = fmaf(w2.w, av, a[11]);
        a[12] = fmaf(w3.x, av, a[12]); a[13] = fmaf(w3.y, av, a[13]);
        a[14] = fmaf(w3.z, av, a[14]); a[15] = fmaf(w3.w, av, a[15]);
    }
    float* zb = zd + ((size_t)b * 2056 + o0) * TT + t;
#pragma unroll
    for (int j = 0; j < 16; j++)
        if (o0 + j < 2056) zb[(size_t)j * TT] = a[j];
}

// ---------------- dense2 (2056 -> 11): z only, t-parallel -------------------
__global__ __launch_bounds__(256) void dense2_z(const float* __restrict__ s4,
                                                const float* __restrict__ w,
                                                float* __restrict__ z4) {
    const int o = blockIdx.x, b = blockIdx.y;
    const int t = threadIdx.x & 63, grp = threadIdx.x >> 6;
    const float* src = s4 + (size_t)b * 2056 * TT;
    const float* wp = w + (size_t)o * 2056;
    float acc = 0.f;
    for (int i = grp; i < 2056; i += 4) acc = fmaf(wp[i], src[(size_t)i * TT + t], acc);
    __shared__ float red[256];
    red[threadIdx.x] = acc;
    __syncthreads();
    if (threadIdx.x < 64) {
        float z = red[threadIdx.x] + red[threadIdx.x + 64] + red[threadIdx.x + 128] +
                  red[threadIdx.x + 192];
        z4[((size_t)b * 11 + o) * TT + threadIdx.x] = z;
    }
}

// ---------------- final CUBA over dense2 output (176 neurons) ---------------
__global__ __launch_bounds__(256) void cuba_out(const float* __restrict__ z4,
                                                float* __restrict__ out) {
    const int n = threadIdx.x;
    if (n < 176) {
        const float4* zp = (const float4*)(z4 + (size_t)n * TT);
        float4* sp = (float4*)(out + (size_t)n * TT);
        float c = 0.f, v = 0.f;
        for (int tc = 0; tc < 4; tc++) {
            float4 a0 = zp[tc * 4 + 0], a1 = zp[tc * 4 + 1];
            float4 a2 = zp[tc * 4 + 2], a3 = zp[tc * 4 + 3];
            scan4(c, v, a0); scan4(c, v, a1); scan4(c, v, a2); scan4(c, v, a3);
            sp[tc * 4 + 0] = a0; sp[tc * 4 + 1] = a1;
            sp[tc * 4 + 2] = a2; sp[tc * 4 + 3] = a3;
        }
    }
}

extern "C" void kernel_launch(void* const* d_in, const int* in_sizes, int n_in,
                              void* d_out, int out_size, void* d_ws, size_t ws_size,
                              hipStream_t stream) {
    const float* x   = (const float*)d_in[0];
    const float* c1v = (const float*)d_in[1];  const float* c1g = (const float*)d_in[2];
    const float* c2v = (const float*)d_in[3];  const float* c2g = (const float*)d_in[4];
    const float* c3v = (const float*)d_in[5];  const float* c3g = (const float*)d_in[6];
    const float* d1v = (const float*)d_in[7];  const float* d1g = (const float*)d_in[8];
    const float* d2v = (const float*)d_in[9];  const float* d2g = (const float*)d_in[10];

    float* ws = (float*)d_ws;
    // weight region W
    float* w1T  = ws + 0;        // (50,8)    = 400
    float* w2T  = ws + 400;      // (200,32)  = 6400
    float* w3T  = ws + 6800;     // (800,64)  = 51200
    float* wd1T = ws + 58000;    // (256,2056)= 526336
    float* wd2  = ws + 584336;   // (11,2056) = 22616
    // region A (8,388,608 floats) and region B (4,194,304 floats), multiplexed
    float* A = ws + 606952;
    float* B = A + 8388608;
    float* s1  = A;              // conv1 spikes (b,8,32,32,t)
    float* s3  = A;              // dense-in spikes (b,256,t)    [after s1 dead]
    float* s4  = A + 262144;     // dense1 spikes (b,2056,t)
    float* z2  = B;              // conv2 pre-act (b,32,64,t)
    float* s2  = B + 2097152;    // conv2 spikes
    float* z3  = B;              // conv3 pre-act (b,256,t)      [after z2 dead]
    float* zd1 = B;              // dense1 pre-act (b,2056,t)    [after z3,s2 dead]
    float* z4  = B;              // dense2 pre-act (b,11,t)      [after zd1 dead]
    (void)ws_size; (void)in_sizes; (void)n_in; (void)out_size;

    // normalized weights (transposed where the z-kernels want (K,O))
    wnorm<true> <<<dim3(8),    dim3(256), 0, stream>>>(c1v, c1g, w1T, 8, 50);
    wnorm<true> <<<dim3(32),   dim3(256), 0, stream>>>(c2v, c2g, w2T, 32, 200);
    wnorm<true> <<<dim3(64),   dim3(256), 0, stream>>>(c3v, c3g, w3T, 64, 800);
    wnorm<true> <<<dim3(2056), dim3(256), 0, stream>>>(d1v, d1g, wd1T, 2056, 256);
    wnorm<false><<<dim3(11),   dim3(256), 0, stream>>>(d2v, d2g, wd2, 11, 2056);

    // pipeline
    conv1_cuba<<<dim3(4096), dim3(256), 0, stream>>>(x, w1T, s1);
    conv2_z   <<<dim3(512),  dim3(256), 0, stream>>>(s1, w2T, z2);
    scan_s    <<<dim3(128),  dim3(256), 0, stream>>>(z2, s2, 32768);
    conv3_z   <<<dim3(128),  dim3(256), 0, stream>>>(s2, w3T, z3);
    scan_s    <<<dim3(16),   dim3(256), 0, stream>>>(z3, s3, 4096);
    dense1_z  <<<dim3(516),  dim3(256), 0, stream>>>(s3, wd1T, zd1);
    scan_s    <<<dim3(129),  dim3(256), 0, stream>>>(zd1, s4, 32896);
    dense2_z  <<<dim3(11, 16), dim3(256), 0, stream>>>(s4, wd2, z4);
    cuba_out  <<<dim3(1), dim3(256), 0, stream>>>(z4, (float*)d_out);
}

// Round 4
// 415.395 us; speedup vs baseline: 3.2865x; 1.2559x over previous
//
#include <hip/hip_runtime.h>
#include <cstddef>

#define TT 64  // timesteps

// ---------------- CUBA LIF step helpers ----------------
__device__ __forceinline__ void scanc(float& c, float& v, float& z) {
    c = fmaf(0.7f, c, z);
    v = fmaf(0.75f, v, c);
    float s = (v >= 1.0f) ? 1.0f : 0.0f;
    v = (v >= 1.0f) ? 0.0f : v;
    z = s;
}
__device__ __forceinline__ void scan4(float& c, float& v, float4& a) {
    scanc(c, v, a.x); scanc(c, v, a.y); scanc(c, v, a.z); scanc(c, v, a.w);
}

// ---------------- weight_norm (per output channel) --------------------------
// TR=true stores transposed (K,O) with leading dim LD (pad LD>O for alignment).
template <bool TR>
__global__ __launch_bounds__(256) void wnorm(const float* __restrict__ v,
                                             const float* __restrict__ g,
                                             float* __restrict__ w, int O, int K,
                                             int LD) {
    __shared__ float red[256];
    const int o = blockIdx.x;
    float s = 0.f;
    for (int k = threadIdx.x; k < K; k += 256) {
        float x = v[(size_t)o * K + k];
        s += x * x;
    }
    red[threadIdx.x] = s;
    __syncthreads();
    for (int off = 128; off > 0; off >>= 1) {
        if (threadIdx.x < off) red[threadIdx.x] += red[threadIdx.x + off];
        __syncthreads();
    }
    const float scale = g[o] / sqrtf(red[0]);
    for (int k = threadIdx.x; k < K; k += 256) {
        float val = scale * v[(size_t)o * K + k];
        if (TR) w[(size_t)k * LD + o] = val;
        else    w[(size_t)o * K + k] = val;
    }
}

// ---------------- conv1 (2->8, 128x128 -> 32x32) fused with CUBA -----------
__global__ __launch_bounds__(256) void conv1_cuba(const float* __restrict__ x,
                                                  const float* __restrict__ w1T,
                                                  float* __restrict__ s1) {
    __shared__ float lds[4][8][68];
    const int wid = threadIdx.x >> 6, t = threadIdx.x & 63;
    const int task = blockIdx.x * 4 + wid;  // 0..16383
    const int spi = task & 1023, b = task >> 10;
    const int oy = spi >> 5, ox = spi & 31;

    float a0=0,a1=0,a2=0,a3=0,a4=0,a5=0,a6=0,a7=0;
    const float* xb = x + (size_t)b * 2 * 128 * 128 * TT + t;

    for (int ci = 0; ci < 2; ci++) {
#pragma unroll
        for (int ky = 0; ky < 5; ky++) {
            const int iy = oy * 4 + ky - 1;
            if (iy < 0 || iy >= 128) continue;
#pragma unroll
            for (int kx = 0; kx < 5; kx++) {
                const int ix = ox * 4 + kx - 1;
                if (ix < 0 || ix >= 128) continue;
                const float xv = xb[((size_t)((ci * 128 + iy) * 128 + ix)) * TT];
                const float4* wp = (const float4*)(w1T + (ci * 25 + ky * 5 + kx) * 8);
                const float4 wA = wp[0], wB = wp[1];
                a0 = fmaf(wA.x, xv, a0); a1 = fmaf(wA.y, xv, a1);
                a2 = fmaf(wA.z, xv, a2); a3 = fmaf(wA.w, xv, a3);
                a4 = fmaf(wB.x, xv, a4); a5 = fmaf(wB.y, xv, a5);
                a6 = fmaf(wB.z, xv, a6); a7 = fmaf(wB.w, xv, a7);
            }
        }
    }
    lds[wid][0][t] = a0; lds[wid][1][t] = a1; lds[wid][2][t] = a2; lds[wid][3][t] = a3;
    lds[wid][4][t] = a4; lds[wid][5][t] = a5; lds[wid][6][t] = a6; lds[wid][7][t] = a7;
    __syncthreads();
    if (t < 8) {
        const int ch = t;
        float4 r[16];
#pragma unroll
        for (int j = 0; j < 16; j++) r[j] = *(const float4*)&lds[wid][ch][j * 4];
        float c = 0.f, v = 0.f;
#pragma unroll
        for (int j = 0; j < 16; j++) scan4(c, v, r[j]);
        float4* op = (float4*)(s1 + (((size_t)b * 8 + ch) * 1024 + spi) * TT);
#pragma unroll
        for (int j = 0; j < 16; j++) op[j] = r[j];
    }
}

// ---------------- conv2 z (8->32, 32x32 -> 8x8), t-parallel, 16 o/wave -----
__global__ __launch_bounds__(256) void conv2_z(const float* __restrict__ s1,
                                               const float* __restrict__ w2T,
                                               float* __restrict__ z2) {
    const int wid = threadIdx.x >> 6, t = threadIdx.x & 63;
    const int task = blockIdx.x * 4 + wid;  // 0..2047
    const int og = task & 1;
    const int spi = (task >> 1) & 63;
    const int b = task >> 7;
    const int oy = spi >> 3, ox = spi & 7;

    float a[16];
#pragma unroll
    for (int j = 0; j < 16; j++) a[j] = 0.f;
    const float* xb = s1 + (size_t)b * 8 * 32 * 32 * TT + t;

    for (int ci = 0; ci < 8; ci++) {
#pragma unroll
        for (int ky = 0; ky < 5; ky++) {
            const int iy = oy * 4 + ky - 1;
            if (iy < 0 || iy >= 32) continue;
#pragma unroll
            for (int kx = 0; kx < 5; kx++) {
                const int ix = ox * 4 + kx - 1;
                if (ix < 0 || ix >= 32) continue;
                const float xv = xb[((size_t)((ci * 32 + iy) * 32 + ix)) * TT];
                const float4* wp =
                    (const float4*)(w2T + (ci * 25 + ky * 5 + kx) * 32 + og * 16);
                const float4 w0 = wp[0], w1 = wp[1], w2 = wp[2], w3 = wp[3];
                a[0]  = fmaf(w0.x, xv, a[0]);  a[1]  = fmaf(w0.y, xv, a[1]);
                a[2]  = fmaf(w0.z, xv, a[2]);  a[3]  = fmaf(w0.w, xv, a[3]);
                a[4]  = fmaf(w1.x, xv, a[4]);  a[5]  = fmaf(w1.y, xv, a[5]);
                a[6]  = fmaf(w1.z, xv, a[6]);  a[7]  = fmaf(w1.w, xv, a[7]);
                a[8]  = fmaf(w2.x, xv, a[8]);  a[9]  = fmaf(w2.y, xv, a[9]);
                a[10] = fmaf(w2.z, xv, a[10]); a[11] = fmaf(w2.w, xv, a[11]);
                a[12] = fmaf(w3.x, xv, a[12]); a[13] = fmaf(w3.y, xv, a[13]);
                a[14] = fmaf(w3.z, xv, a[14]); a[15] = fmaf(w3.w, xv, a[15]);
            }
        }
    }
    float* zb = z2 + (((size_t)b * 32 + og * 16) * 64 + spi) * TT + t;
#pragma unroll
    for (int j = 0; j < 16; j++) zb[(size_t)j * 64 * TT] = a[j];
}

// ---------------- conv3 z (32->64, 8x8 -> 2x2), t-parallel, 8 o/wave -------
__global__ __launch_bounds__(256) void conv3_z(const float* __restrict__ s2,
                                               const float* __restrict__ wT,
                                               float* __restrict__ z3) {
    const int t = threadIdx.x & 63;
    const int task = blockIdx.x * 4 + (threadIdx.x >> 6);  // 0..511
    const int og = task & 7;
    const int spi = (task >> 3) & 3;
    const int b = task >> 5;
    const int oy = spi >> 1, ox = spi & 1;

    float acc0 = 0, acc1 = 0, acc2 = 0, acc3 = 0, acc4 = 0, acc5 = 0, acc6 = 0, acc7 = 0;
    const float* xb = s2 + (size_t)b * 32 * 8 * 8 * TT + t;

    for (int ci = 0; ci < 32; ci++) {
#pragma unroll
        for (int ky = 0; ky < 5; ky++) {
            const int iy = oy * 4 + ky - 1;
            if (iy < 0 || iy >= 8) continue;
#pragma unroll
            for (int kx = 0; kx < 5; kx++) {
                const int ix = ox * 4 + kx - 1;
                if (ix < 0 || ix >= 8) continue;
                const float xv = xb[((size_t)((ci * 8 + iy) * 8 + ix)) * TT];
                const float4* wp =
                    (const float4*)(wT + ((ci * 25 + ky * 5 + kx)) * 64 + og * 8);
                const float4 wA = wp[0], wB = wp[1];
                acc0 = fmaf(wA.x, xv, acc0); acc1 = fmaf(wA.y, xv, acc1);
                acc2 = fmaf(wA.z, xv, acc2); acc3 = fmaf(wA.w, xv, acc3);
                acc4 = fmaf(wB.x, xv, acc4); acc5 = fmaf(wB.y, xv, acc5);
                acc6 = fmaf(wB.z, xv, acc6); acc7 = fmaf(wB.w, xv, acc7);
            }
        }
    }
    float* zb = z3 + ((size_t)b * 256 + (size_t)og * 32 + spi) * TT + t;
    zb[0 * 4 * TT] = acc0; zb[1 * 4 * TT] = acc1; zb[2 * 4 * TT] = acc2;
    zb[3 * 4 * TT] = acc3; zb[4 * 4 * TT] = acc4; zb[5 * 4 * TT] = acc5;
    zb[6 * 4 * TT] = acc6; zb[7 * 4 * TT] = acc7;
}

// ---------------- generic de-fused CUBA scan: z (N,64) -> spikes (N,64) -----
__global__ __launch_bounds__(256) void scan_s(const float* __restrict__ z,
                                              float* __restrict__ s, int N) {
    const int n = blockIdx.x * 256 + threadIdx.x;
    if (n >= N) return;
    const float4* zp = (const float4*)(z + (size_t)n * TT);
    float4* sp = (float4*)(s + (size_t)n * TT);
    float c = 0.f, v = 0.f;
    for (int tc = 0; tc < 4; tc++) {
        float4 a0 = zp[tc * 4 + 0], a1 = zp[tc * 4 + 1];
        float4 a2 = zp[tc * 4 + 2], a3 = zp[tc * 4 + 3];
        scan4(c, v, a0); scan4(c, v, a1); scan4(c, v, a2); scan4(c, v, a3);
        sp[tc * 4 + 0] = a0; sp[tc * 4 + 1] = a1;
        sp[tc * 4 + 2] = a2; sp[tc * 4 + 3] = a3;
    }
}

// ---------------- dense1 z (256 -> 2056), t-parallel, 16 o/wave -------------
__global__ __launch_bounds__(256) void dense1_z(const float* __restrict__ s3,
                                                const float* __restrict__ wT,
                                                float* __restrict__ zd) {
    const int wid = threadIdx.x >> 6, t = threadIdx.x & 63;
    const int task = blockIdx.x * 4 + wid;  // 0..2063
    const int b = task / 129;
    const int og = task - b * 129;
    const int o0 = og * 16;

    float a[16];
#pragma unroll
    for (int j = 0; j < 16; j++) a[j] = 0.f;
    const float* ab = s3 + (size_t)b * 256 * TT + t;

    for (int i = 0; i < 256; i++) {
        const float av = ab[(size_t)i * TT];
        const float4* wp = (const float4*)(wT + (size_t)i * 2056 + o0);
        const float4 w0 = wp[0], w1 = wp[1], w2 = wp[2], w3 = wp[3];
        a[0]  = fmaf(w0.x, av, a[0]);  a[1]  = fmaf(w0.y, av, a[1]);
        a[2]  = fmaf(w0.z, av, a[2]);  a[3]  = fmaf(w0.w, av, a[3]);
        a[4]  = fmaf(w1.x, av, a[4]);  a[5]  = fmaf(w1.y, av, a[5]);
        a[6]  = fmaf(w1.z, av, a[6]);  a[7]  = fmaf(w1.w, av, a[7]);
        a[8]  = fmaf(w2.x, av, a[8]);  a[9]  = fmaf(w2.y, av, a[9]);
        a[10] = fmaf(w2.z, av, a[10]); a[11] = fmaf(w2.w, av, a[11]);
        a[12] = fmaf(w3.x, av, a[12]); a[13] = fmaf(w3.y, av, a[13]);
        a[14] = fmaf(w3.z, av, a[14]); a[15] = fmaf(w3.w, av, a[15]);
    }
    float* zb = zd + ((size_t)b * 2056 + o0) * TT + t;
#pragma unroll
    for (int j = 0; j < 16; j++)
        if (o0 + j < 2056) zb[(size_t)j * TT] = a[j];
}

// ---------------- dense2 stage 1: split-K partial sums ----------------------
// grid (8 splits, 16 b); wave = 64 t-lanes; thread accumulates all 11 outputs
// over its i-slice (stride 4 across the block's 4 waves). Weights padded (i,12)
// so each i's 11 weights are 3 aligned broadcast float4 loads. Activations
// read exactly once per (b, i, t). Deterministic LDS wave-tree reduce.
__global__ __launch_bounds__(256) void dense2_part(const float* __restrict__ s4,
                                                   const float* __restrict__ wP,
                                                   float* __restrict__ z4p) {
    __shared__ float red[4][11][64];
    const int sp = blockIdx.x, b = blockIdx.y;
    const int w = threadIdx.x >> 6, t = threadIdx.x & 63;
    const int i0 = sp * 257, iend = i0 + 257;  // 2056 = 8*257
    const float* src = s4 + (size_t)b * 2056 * TT + t;

    float acc[11];
#pragma unroll
    for (int j = 0; j < 11; j++) acc[j] = 0.f;

    for (int i = i0 + w; i < iend; i += 4) {
        const float xv = src[(size_t)i * TT];
        const float4* wp = (const float4*)(wP + (size_t)i * 12);
        const float4 w0 = wp[0], w1 = wp[1], w2 = wp[2];
        acc[0]  = fmaf(w0.x, xv, acc[0]);  acc[1]  = fmaf(w0.y, xv, acc[1]);
        acc[2]  = fmaf(w0.z, xv, acc[2]);  acc[3]  = fmaf(w0.w, xv, acc[3]);
        acc[4]  = fmaf(w1.x, xv, acc[4]);  acc[5]  = fmaf(w1.y, xv, acc[5]);
        acc[6]  = fmaf(w1.z, xv, acc[6]);  acc[7]  = fmaf(w1.w, xv, acc[7]);
        acc[8]  = fmaf(w2.x, xv, acc[8]);  acc[9]  = fmaf(w2.y, xv, acc[9]);
        acc[10] = fmaf(w2.z, xv, acc[10]);
    }
#pragma unroll
    for (int j = 0; j < 11; j++) red[w][j][t] = acc[j];
    __syncthreads();
    if (w == 0) {
#pragma unroll
        for (int j = 0; j < 11; j++) {
            const float s = red[0][j][t] + red[1][j][t] + red[2][j][t] + red[3][j][t];
            z4p[(((size_t)b * 8 + sp) * 11 + j) * TT + t] = s;
        }
    }
}

// ---------------- dense2 stage 2: fixed-order reduce + final CUBA scan ------
__global__ __launch_bounds__(256) void dense2_scan(const float* __restrict__ z4p,
                                                   float* __restrict__ out) {
    __shared__ float z[11][64];
    const int b = blockIdx.x;
    for (int idx = threadIdx.x; idx < 11 * 64; idx += 256) {
        const int o = idx >> 6, t = idx & 63;
        float s = 0.f;
#pragma unroll
        for (int sp = 0; sp < 8; sp++)
            s += z4p[(((size_t)b * 8 + sp) * 11 + o) * TT + t];
        z[o][t] = s;
    }
    __syncthreads();
    if (threadIdx.x < 11) {
        const int o = threadIdx.x;
        float c = 0.f, v = 0.f;
        float* op = out + ((size_t)b * 11 + o) * TT;
#pragma unroll
        for (int t = 0; t < TT; t++) {
            float zz = z[o][t];
            scanc(c, v, zz);
            op[t] = zz;
        }
    }
}

extern "C" void kernel_launch(void* const* d_in, const int* in_sizes, int n_in,
                              void* d_out, int out_size, void* d_ws, size_t ws_size,
                              hipStream_t stream) {
    const float* x   = (const float*)d_in[0];
    const float* c1v = (const float*)d_in[1];  const float* c1g = (const float*)d_in[2];
    const float* c2v = (const float*)d_in[3];  const float* c2g = (const float*)d_in[4];
    const float* c3v = (const float*)d_in[5];  const float* c3g = (const float*)d_in[6];
    const float* d1v = (const float*)d_in[7];  const float* d1g = (const float*)d_in[8];
    const float* d2v = (const float*)d_in[9];  const float* d2g = (const float*)d_in[10];

    float* ws = (float*)d_ws;
    // weight region
    float* w1T  = ws + 0;        // (50,8)     = 400
    float* w2T  = ws + 400;      // (200,32)   = 6400
    float* w3T  = ws + 6800;     // (800,64)   = 51200
    float* wd1T = ws + 58000;    // (256,2056) = 526336
    float* wd2P = ws + 584336;   // (2056,12) padded = 24672
    // region A (8,388,608 floats) and region B (4,194,304 floats), multiplexed
    float* A = ws + 609008;
    float* B = A + 8388608;
    float* s1  = A;              // conv1 spikes (b,8,32,32,t)
    float* s3  = A;              // dense-in spikes (b,256,t)    [after s1 dead]
    float* s4  = A + 262144;     // dense1 spikes (b,2056,t)
    float* z2  = B;              // conv2 pre-act (b,32,64,t)
    float* s2  = B + 2097152;    // conv2 spikes
    float* z3  = B;              // conv3 pre-act (b,256,t)      [after z2 dead]
    float* zd1 = B;              // dense1 pre-act (b,2056,t)    [after z3,s2 dead]
    float* z4p = B;              // dense2 partials (b,8,11,t)   [after zd1 dead]
    (void)ws_size; (void)in_sizes; (void)n_in; (void)out_size;

    // normalized weights (transposed (K,O) where the z-kernels want it)
    wnorm<true> <<<dim3(8),    dim3(256), 0, stream>>>(c1v, c1g, w1T, 8, 50, 8);
    wnorm<true> <<<dim3(32),   dim3(256), 0, stream>>>(c2v, c2g, w2T, 32, 200, 32);
    wnorm<true> <<<dim3(64),   dim3(256), 0, stream>>>(c3v, c3g, w3T, 64, 800, 64);
    wnorm<true> <<<dim3(2056), dim3(256), 0, stream>>>(d1v, d1g, wd1T, 2056, 256, 2056);
    wnorm<true> <<<dim3(11),   dim3(256), 0, stream>>>(d2v, d2g, wd2P, 11, 2056, 12);

    // pipeline
    conv1_cuba <<<dim3(4096), dim3(256), 0, stream>>>(x, w1T, s1);
    conv2_z    <<<dim3(512),  dim3(256), 0, stream>>>(s1, w2T, z2);
    scan_s     <<<dim3(128),  dim3(256), 0, stream>>>(z2, s2, 32768);
    conv3_z    <<<dim3(128),  dim3(256), 0, stream>>>(s2, w3T, z3);
    scan_s     <<<dim3(16),   dim3(256), 0, stream>>>(z3, s3, 4096);
    dense1_z   <<<dim3(516),  dim3(256), 0, stream>>>(s3, wd1T, zd1);
    scan_s     <<<dim3(129),  dim3(256), 0, stream>>>(zd1, s4, 32896);
    dense2_part<<<dim3(8, 16), dim3(256), 0, stream>>>(s4, wd2P, z4p);
    dense2_scan<<<dim3(16),   dim3(256), 0, stream>>>(z4p, (float*)d_out);
}

// Round 5
// 402.191 us; speedup vs baseline: 3.3944x; 1.0328x over previous
//
#include <hip/hip_runtime.h>
#include <cstddef>

#define TT 64  // timesteps

// ---------------- CUBA LIF step helpers ----------------
__device__ __forceinline__ void scanc(float& c, float& v, float& z) {
    c = fmaf(0.7f, c, z);
    v = fmaf(0.75f, v, c);
    float s = (v >= 1.0f) ? 1.0f : 0.0f;
    v = (v >= 1.0f) ? 0.0f : v;
    z = s;
}
__device__ __forceinline__ void scan4(float& c, float& v, float4& a) {
    scanc(c, v, a.x); scanc(c, v, a.y); scanc(c, v, a.z); scanc(c, v, a.w);
}

// ---------------- weight_norm (per output channel) --------------------------
template <bool TR>
__global__ __launch_bounds__(256) void wnorm(const float* __restrict__ v,
                                             const float* __restrict__ g,
                                             float* __restrict__ w, int O, int K,
                                             int LD) {
    __shared__ float red[256];
    const int o = blockIdx.x;
    float s = 0.f;
    for (int k = threadIdx.x; k < K; k += 256) {
        float x = v[(size_t)o * K + k];
        s += x * x;
    }
    red[threadIdx.x] = s;
    __syncthreads();
    for (int off = 128; off > 0; off >>= 1) {
        if (threadIdx.x < off) red[threadIdx.x] += red[threadIdx.x + off];
        __syncthreads();
    }
    const float scale = g[o] / sqrtf(red[0]);
    for (int k = threadIdx.x; k < K; k += 256) {
        float val = scale * v[(size_t)o * K + k];
        if (TR) w[(size_t)k * LD + o] = val;
        else    w[(size_t)o * K + k] = val;
    }
}

// ---------------- conv1 (2->8, 128x128 -> 32x32) fused with CUBA -----------
// Wave = (b,oy,ox); lane = t. Interior waves (oy>=1 && ox>=1; 961/1024) take a
// branch-free path: all 50 tap loads issued into registers up front (latency
// hidden by ~50 outstanding loads), then the FMA chain in the exact same
// ci->ky->kx order as the guarded path -> bit-identical accumulation.
__global__ __launch_bounds__(256) void conv1_cuba(const float* __restrict__ x,
                                                  const float* __restrict__ w1T,
                                                  float* __restrict__ s1) {
    __shared__ float lds[4][8][68];
    const int wid = threadIdx.x >> 6, t = threadIdx.x & 63;
    const int task = blockIdx.x * 4 + wid;  // 0..16383
    const int spi = task & 1023, b = task >> 10;
    const int oy = spi >> 5, ox = spi & 31;

    float a0=0,a1=0,a2=0,a3=0,a4=0,a5=0,a6=0,a7=0;
    const float* xb = x + (size_t)b * 2 * 128 * 128 * TT + t;

    if (oy >= 1 && ox >= 1) {
        const float* xq = xb + ((size_t)((oy * 4 - 1) * 128 + ox * 4 - 1)) * TT;
        float xv[50];
#pragma unroll
        for (int ci = 0; ci < 2; ci++)
#pragma unroll
            for (int ky = 0; ky < 5; ky++)
#pragma unroll
                for (int kx = 0; kx < 5; kx++)
                    xv[ci * 25 + ky * 5 + kx] =
                        xq[((size_t)(ci * 16384 + ky * 128 + kx)) * TT];
#pragma unroll
        for (int k = 0; k < 50; k++) {
            const float4* wp = (const float4*)(w1T + k * 8);
            const float4 wA = wp[0], wB = wp[1];
            const float xvk = xv[k];
            a0 = fmaf(wA.x, xvk, a0); a1 = fmaf(wA.y, xvk, a1);
            a2 = fmaf(wA.z, xvk, a2); a3 = fmaf(wA.w, xvk, a3);
            a4 = fmaf(wB.x, xvk, a4); a5 = fmaf(wB.y, xvk, a5);
            a6 = fmaf(wB.z, xvk, a6); a7 = fmaf(wB.w, xvk, a7);
        }
    } else {
        for (int ci = 0; ci < 2; ci++) {
#pragma unroll
            for (int ky = 0; ky < 5; ky++) {
                const int iy = oy * 4 + ky - 1;
                if (iy < 0 || iy >= 128) continue;
#pragma unroll
                for (int kx = 0; kx < 5; kx++) {
                    const int ix = ox * 4 + kx - 1;
                    if (ix < 0 || ix >= 128) continue;
                    const float xvk = xb[((size_t)((ci * 128 + iy) * 128 + ix)) * TT];
                    const float4* wp = (const float4*)(w1T + (ci * 25 + ky * 5 + kx) * 8);
                    const float4 wA = wp[0], wB = wp[1];
                    a0 = fmaf(wA.x, xvk, a0); a1 = fmaf(wA.y, xvk, a1);
                    a2 = fmaf(wA.z, xvk, a2); a3 = fmaf(wA.w, xvk, a3);
                    a4 = fmaf(wB.x, xvk, a4); a5 = fmaf(wB.y, xvk, a5);
                    a6 = fmaf(wB.z, xvk, a6); a7 = fmaf(wB.w, xvk, a7);
                }
            }
        }
    }
    lds[wid][0][t] = a0; lds[wid][1][t] = a1; lds[wid][2][t] = a2; lds[wid][3][t] = a3;
    lds[wid][4][t] = a4; lds[wid][5][t] = a5; lds[wid][6][t] = a6; lds[wid][7][t] = a7;
    __syncthreads();
    if (t < 8) {
        const int ch = t;
        float4 r[16];
#pragma unroll
        for (int j = 0; j < 16; j++) r[j] = *(const float4*)&lds[wid][ch][j * 4];
        float c = 0.f, v = 0.f;
#pragma unroll
        for (int j = 0; j < 16; j++) scan4(c, v, r[j]);
        float4* op = (float4*)(s1 + (((size_t)b * 8 + ch) * 1024 + spi) * TT);
#pragma unroll
        for (int j = 0; j < 16; j++) op[j] = r[j];
    }
}

// ---------------- conv2 z (8->32, 32x32 -> 8x8), t-parallel, 16 o/wave -----
// Interior fast path: ci processed in pairs, 50 tap loads in flight.
__global__ __launch_bounds__(256) void conv2_z(const float* __restrict__ s1,
                                               const float* __restrict__ w2T,
                                               float* __restrict__ z2) {
    const int wid = threadIdx.x >> 6, t = threadIdx.x & 63;
    const int task = blockIdx.x * 4 + wid;  // 0..2047
    const int og = task & 1;
    const int spi = (task >> 1) & 63;
    const int b = task >> 7;
    const int oy = spi >> 3, ox = spi & 7;

    float a[16];
#pragma unroll
    for (int j = 0; j < 16; j++) a[j] = 0.f;
    const float* xb = s1 + (size_t)b * 8 * 32 * 32 * TT + t;

    if (oy >= 1 && ox >= 1) {
        const float* xq = xb + ((size_t)((oy * 4 - 1) * 32 + ox * 4 - 1)) * TT;
        for (int cp = 0; cp < 4; cp++) {  // ci pairs: (0,1),(2,3),(4,5),(6,7)
            float xv[50];
#pragma unroll
            for (int cc = 0; cc < 2; cc++)
#pragma unroll
                for (int ky = 0; ky < 5; ky++)
#pragma unroll
                    for (int kx = 0; kx < 5; kx++)
                        xv[cc * 25 + ky * 5 + kx] =
                            xq[((size_t)(((cp * 2 + cc) * 1024) + ky * 32 + kx)) * TT];
#pragma unroll
            for (int k = 0; k < 50; k++) {
                const int row = (cp * 2 + (k >= 25 ? 1 : 0)) * 25 + (k >= 25 ? k - 25 : k);
                const float4* wp = (const float4*)(w2T + row * 32 + og * 16);
                const float4 w0 = wp[0], w1 = wp[1], w2 = wp[2], w3 = wp[3];
                const float xvk = xv[k];
                a[0]  = fmaf(w0.x, xvk, a[0]);  a[1]  = fmaf(w0.y, xvk, a[1]);
                a[2]  = fmaf(w0.z, xvk, a[2]);  a[3]  = fmaf(w0.w, xvk, a[3]);
                a[4]  = fmaf(w1.x, xvk, a[4]);  a[5]  = fmaf(w1.y, xvk, a[5]);
                a[6]  = fmaf(w1.z, xvk, a[6]);  a[7]  = fmaf(w1.w, xvk, a[7]);
                a[8]  = fmaf(w2.x, xvk, a[8]);  a[9]  = fmaf(w2.y, xvk, a[9]);
                a[10] = fmaf(w2.z, xvk, a[10]); a[11] = fmaf(w2.w, xvk, a[11]);
                a[12] = fmaf(w3.x, xvk, a[12]); a[13] = fmaf(w3.y, xvk, a[13]);
                a[14] = fmaf(w3.z, xvk, a[14]); a[15] = fmaf(w3.w, xvk, a[15]);
            }
        }
    } else {
        for (int ci = 0; ci < 8; ci++) {
#pragma unroll
            for (int ky = 0; ky < 5; ky++) {
                const int iy = oy * 4 + ky - 1;
                if (iy < 0 || iy >= 32) continue;
#pragma unroll
                for (int kx = 0; kx < 5; kx++) {
                    const int ix = ox * 4 + kx - 1;
                    if (ix < 0 || ix >= 32) continue;
                    const float xvk = xb[((size_t)((ci * 32 + iy) * 32 + ix)) * TT];
                    const float4* wp =
                        (const float4*)(w2T + (ci * 25 + ky * 5 + kx) * 32 + og * 16);
                    const float4 w0 = wp[0], w1 = wp[1], w2 = wp[2], w3 = wp[3];
                    a[0]  = fmaf(w0.x, xvk, a[0]);  a[1]  = fmaf(w0.y, xvk, a[1]);
                    a[2]  = fmaf(w0.z, xvk, a[2]);  a[3]  = fmaf(w0.w, xvk, a[3]);
                    a[4]  = fmaf(w1.x, xvk, a[4]);  a[5]  = fmaf(w1.y, xvk, a[5]);
                    a[6]  = fmaf(w1.z, xvk, a[6]);  a[7]  = fmaf(w1.w, xvk, a[7]);
                    a[8]  = fmaf(w2.x, xvk, a[8]);  a[9]  = fmaf(w2.y, xvk, a[9]);
                    a[10] = fmaf(w2.z, xvk, a[10]); a[11] = fmaf(w2.w, xvk, a[11]);
                    a[12] = fmaf(w3.x, xvk, a[12]); a[13] = fmaf(w3.y, xvk, a[13]);
                    a[14] = fmaf(w3.z, xvk, a[14]); a[15] = fmaf(w3.w, xvk, a[15]);
                }
            }
        }
    }
    float* zb = z2 + (((size_t)b * 32 + og * 16) * 64 + spi) * TT + t;
#pragma unroll
    for (int j = 0; j < 16; j++) zb[(size_t)j * 64 * TT] = a[j];
}

// ---------------- conv3 z (32->64, 8x8 -> 2x2), t-parallel, 8 o/wave -------
__global__ __launch_bounds__(256) void conv3_z(const float* __restrict__ s2,
                                               const float* __restrict__ wT,
                                               float* __restrict__ z3) {
    const int t = threadIdx.x & 63;
    const int task = blockIdx.x * 4 + (threadIdx.x >> 6);  // 0..511
    const int og = task & 7;
    const int spi = (task >> 3) & 3;
    const int b = task >> 5;
    const int oy = spi >> 1, ox = spi & 1;

    float acc0 = 0, acc1 = 0, acc2 = 0, acc3 = 0, acc4 = 0, acc5 = 0, acc6 = 0, acc7 = 0;
    const float* xb = s2 + (size_t)b * 32 * 8 * 8 * TT + t;

    for (int ci = 0; ci < 32; ci++) {
#pragma unroll
        for (int ky = 0; ky < 5; ky++) {
            const int iy = oy * 4 + ky - 1;
            if (iy < 0 || iy >= 8) continue;
#pragma unroll
            for (int kx = 0; kx < 5; kx++) {
                const int ix = ox * 4 + kx - 1;
                if (ix < 0 || ix >= 8) continue;
                const float xv = xb[((size_t)((ci * 8 + iy) * 8 + ix)) * TT];
                const float4* wp =
                    (const float4*)(wT + ((ci * 25 + ky * 5 + kx)) * 64 + og * 8);
                const float4 wA = wp[0], wB = wp[1];
                acc0 = fmaf(wA.x, xv, acc0); acc1 = fmaf(wA.y, xv, acc1);
                acc2 = fmaf(wA.z, xv, acc2); acc3 = fmaf(wA.w, xv, acc3);
                acc4 = fmaf(wB.x, xv, acc4); acc5 = fmaf(wB.y, xv, acc5);
                acc6 = fmaf(wB.z, xv, acc6); acc7 = fmaf(wB.w, xv, acc7);
            }
        }
    }
    float* zb = z3 + ((size_t)b * 256 + (size_t)og * 32 + spi) * TT + t;
    zb[0 * 4 * TT] = acc0; zb[1 * 4 * TT] = acc1; zb[2 * 4 * TT] = acc2;
    zb[3 * 4 * TT] = acc3; zb[4 * 4 * TT] = acc4; zb[5 * 4 * TT] = acc5;
    zb[6 * 4 * TT] = acc6; zb[7 * 4 * TT] = acc7;
}

// ---------------- generic de-fused CUBA scan: z (N,64) -> spikes (N,64) -----
__global__ __launch_bounds__(256) void scan_s(const float* __restrict__ z,
                                              float* __restrict__ s, int N) {
    const int n = blockIdx.x * 256 + threadIdx.x;
    if (n >= N) return;
    const float4* zp = (const float4*)(z + (size_t)n * TT);
    float4* sp = (float4*)(s + (size_t)n * TT);
    float c = 0.f, v = 0.f;
    for (int tc = 0; tc < 4; tc++) {
        float4 a0 = zp[tc * 4 + 0], a1 = zp[tc * 4 + 1];
        float4 a2 = zp[tc * 4 + 2], a3 = zp[tc * 4 + 3];
        scan4(c, v, a0); scan4(c, v, a1); scan4(c, v, a2); scan4(c, v, a3);
        sp[tc * 4 + 0] = a0; sp[tc * 4 + 1] = a1;
        sp[tc * 4 + 2] = a2; sp[tc * 4 + 3] = a3;
    }
}

// ---------------- dense1 z (256 -> 2056), t-parallel, 16 o/wave -------------
__global__ __launch_bounds__(256) void dense1_z(const float* __restrict__ s3,
                                                const float* __restrict__ wT,
                                                float* __restrict__ zd) {
    const int wid = threadIdx.x >> 6, t = threadIdx.x & 63;
    const int task = blockIdx.x * 4 + wid;  // 0..2063
    const int b = task / 129;
    const int og = task - b * 129;
    const int o0 = og * 16;

    float a[16];
#pragma unroll
    for (int j = 0; j < 16; j++) a[j] = 0.f;
    const float* ab = s3 + (size_t)b * 256 * TT + t;

#pragma unroll 2
    for (int i = 0; i < 256; i++) {
        const float av = ab[(size_t)i * TT];
        const float4* wp = (const float4*)(wT + (size_t)i * 2056 + o0);
        const float4 w0 = wp[0], w1 = wp[1], w2 = wp[2], w3 = wp[3];
        a[0]  = fmaf(w0.x, av, a[0]);  a[1]  = fmaf(w0.y, av, a[1]);
        a[2]  = fmaf(w0.z, av, a[2]);  a[3]  = fmaf(w0.w, av, a[3]);
        a[4]  = fmaf(w1.x, av, a[4]);  a[5]  = fmaf(w1.y, av, a[5]);
        a[6]  = fmaf(w1.z, av, a[6]);  a[7]  = fmaf(w1.w, av, a[7]);
        a[8]  = fmaf(w2.x, av, a[8]);  a[9]  = fmaf(w2.y, av, a[9]);
        a[10] = fmaf(w2.z, av, a[10]); a[11] = fmaf(w2.w, av, a[11]);
        a[12] = fmaf(w3.x, av, a[12]); a[13] = fmaf(w3.y, av, a[13]);
        a[14] = fmaf(w3.z, av, a[14]); a[15] = fmaf(w3.w, av, a[15]);
    }
    float* zb = zd + ((size_t)b * 2056 + o0) * TT + t;
#pragma unroll
    for (int j = 0; j < 16; j++)
        if (o0 + j < 2056) zb[(size_t)j * TT] = a[j];
}

// ---------------- dense2 stage 1: split-K partial sums ----------------------
__global__ __launch_bounds__(256) void dense2_part(const float* __restrict__ s4,
                                                   const float* __restrict__ wP,
                                                   float* __restrict__ z4p) {
    __shared__ float red[4][11][64];
    const int sp = blockIdx.x, b = blockIdx.y;
    const int w = threadIdx.x >> 6, t = threadIdx.x & 63;
    const int i0 = sp * 257, iend = i0 + 257;  // 2056 = 8*257
    const float* src = s4 + (size_t)b * 2056 * TT + t;

    float acc[11];
#pragma unroll
    for (int j = 0; j < 11; j++) acc[j] = 0.f;

    for (int i = i0 + w; i < iend; i += 4) {
        const float xv = src[(size_t)i * TT];
        const float4* wp = (const float4*)(wP + (size_t)i * 12);
        const float4 w0 = wp[0], w1 = wp[1], w2 = wp[2];
        acc[0]  = fmaf(w0.x, xv, acc[0]);  acc[1]  = fmaf(w0.y, xv, acc[1]);
        acc[2]  = fmaf(w0.z, xv, acc[2]);  acc[3]  = fmaf(w0.w, xv, acc[3]);
        acc[4]  = fmaf(w1.x, xv, acc[4]);  acc[5]  = fmaf(w1.y, xv, acc[5]);
        acc[6]  = fmaf(w1.z, xv, acc[6]);  acc[7]  = fmaf(w1.w, xv, acc[7]);
        acc[8]  = fmaf(w2.x, xv, acc[8]);  acc[9]  = fmaf(w2.y, xv, acc[9]);
        acc[10] = fmaf(w2.z, xv, acc[10]);
    }
#pragma unroll
    for (int j = 0; j < 11; j++) red[w][j][t] = acc[j];
    __syncthreads();
    if (w == 0) {
#pragma unroll
        for (int j = 0; j < 11; j++) {
            const float s = red[0][j][t] + red[1][j][t] + red[2][j][t] + red[3][j][t];
            z4p[(((size_t)b * 8 + sp) * 11 + j) * TT + t] = s;
        }
    }
}

// ---------------- dense2 stage 2: fixed-order reduce + final CUBA scan ------
__global__ __launch_bounds__(256) void dense2_scan(const float* __restrict__ z4p,
                                                   float* __restrict__ out) {
    __shared__ float z[11][64];
    const int b = blockIdx.x;
    for (int idx = threadIdx.x; idx < 11 * 64; idx += 256) {
        const int o = idx >> 6, t = idx & 63;
        float s = 0.f;
#pragma unroll
        for (int sp = 0; sp < 8; sp++)
            s += z4p[(((size_t)b * 8 + sp) * 11 + o) * TT + t];
        z[o][t] = s;
    }
    __syncthreads();
    if (threadIdx.x < 11) {
        const int o = threadIdx.x;
        float c = 0.f, v = 0.f;
        float* op = out + ((size_t)b * 11 + o) * TT;
#pragma unroll
        for (int t = 0; t < TT; t++) {
            float zz = z[o][t];
            scanc(c, v, zz);
            op[t] = zz;
        }
    }
}

extern "C" void kernel_launch(void* const* d_in, const int* in_sizes, int n_in,
                              void* d_out, int out_size, void* d_ws, size_t ws_size,
                              hipStream_t stream) {
    const float* x   = (const float*)d_in[0];
    const float* c1v = (const float*)d_in[1];  const float* c1g = (const float*)d_in[2];
    const float* c2v = (const float*)d_in[3];  const float* c2g = (const float*)d_in[4];
    const float* c3v = (const float*)d_in[5];  const float* c3g = (const float*)d_in[6];
    const float* d1v = (const float*)d_in[7];  const float* d1g = (const float*)d_in[8];
    const float* d2v = (const float*)d_in[9];  const float* d2g = (const float*)d_in[10];

    float* ws = (float*)d_ws;
    // weight region
    float* w1T  = ws + 0;        // (50,8)     = 400
    float* w2T  = ws + 400;      // (200,32)   = 6400
    float* w3T  = ws + 6800;     // (800,64)   = 51200
    float* wd1T = ws + 58000;    // (256,2056) = 526336
    float* wd2P = ws + 584336;   // (2056,12) padded = 24672
    // region A (8,388,608 floats) and region B (4,194,304 floats), multiplexed
    float* A = ws + 609008;
    float* B = A + 8388608;
    float* s1  = A;              // conv1 spikes (b,8,32,32,t)
    float* s3  = A;              // dense-in spikes (b,256,t)    [after s1 dead]
    float* s4  = A + 262144;     // dense1 spikes (b,2056,t)
    float* z2  = B;              // conv2 pre-act (b,32,64,t)
    float* s2  = B + 2097152;    // conv2 spikes
    float* z3  = B;              // conv3 pre-act (b,256,t)      [after z2 dead]
    float* zd1 = B;              // dense1 pre-act (b,2056,t)    [after z3,s2 dead]
    float* z4p = B;              // dense2 partials (b,8,11,t)   [after zd1 dead]
    (void)ws_size; (void)in_sizes; (void)n_in; (void)out_size;

    // normalized weights (transposed (K,O) where the z-kernels want it)
    wnorm<true> <<<dim3(8),    dim3(256), 0, stream>>>(c1v, c1g, w1T, 8, 50, 8);
    wnorm<true> <<<dim3(32),   dim3(256), 0, stream>>>(c2v, c2g, w2T, 32, 200, 32);
    wnorm<true> <<<dim3(64),   dim3(256), 0, stream>>>(c3v, c3g, w3T, 64, 800, 64);
    wnorm<true> <<<dim3(2056), dim3(256), 0, stream>>>(d1v, d1g, wd1T, 2056, 256, 2056);
    wnorm<true> <<<dim3(11),   dim3(256), 0, stream>>>(d2v, d2g, wd2P, 11, 2056, 12);

    // pipeline
    conv1_cuba <<<dim3(4096), dim3(256), 0, stream>>>(x, w1T, s1);
    conv2_z    <<<dim3(512),  dim3(256), 0, stream>>>(s1, w2T, z2);
    scan_s     <<<dim3(128),  dim3(256), 0, stream>>>(z2, s2, 32768);
    conv3_z    <<<dim3(128),  dim3(256), 0, stream>>>(s2, w3T, z3);
    scan_s     <<<dim3(16),   dim3(256), 0, stream>>>(z3, s3, 4096);
    dense1_z   <<<dim3(516),  dim3(256), 0, stream>>>(s3, wd1T, zd1);
    scan_s     <<<dim3(129),  dim3(256), 0, stream>>>(zd1, s4, 32896);
    dense2_part<<<dim3(8, 16), dim3(256), 0, stream>>>(s4, wd2P, z4p);
    dense2_scan<<<dim3(16),   dim3(256), 0, stream>>>(z4p, (float*)d_out);
}

// Round 6
// 331.938 us; speedup vs baseline: 4.1128x; 1.2116x over previous
//
#include <hip/hip_runtime.h>
#include <cstddef>

#define TT 64  // timesteps

// ---------------- CUBA LIF step helpers ----------------
__device__ __forceinline__ void scanc(float& c, float& v, float& z) {
    c = fmaf(0.7f, c, z);
    v = fmaf(0.75f, v, c);
    float s = (v >= 1.0f) ? 1.0f : 0.0f;
    v = (v >= 1.0f) ? 0.0f : v;
    z = s;
}
__device__ __forceinline__ void scan4(float& c, float& v, float4& a) {
    scanc(c, v, a.x); scanc(c, v, a.y); scanc(c, v, a.z); scanc(c, v, a.w);
}

// ---------------- weight_norm (per output channel) --------------------------
template <bool TR>
__global__ __launch_bounds__(256) void wnorm(const float* __restrict__ v,
                                             const float* __restrict__ g,
                                             float* __restrict__ w, int O, int K,
                                             int LD) {
    __shared__ float red[256];
    const int o = blockIdx.x;
    float s = 0.f;
    for (int k = threadIdx.x; k < K; k += 256) {
        float x = v[(size_t)o * K + k];
        s += x * x;
    }
    red[threadIdx.x] = s;
    __syncthreads();
    for (int off = 128; off > 0; off >>= 1) {
        if (threadIdx.x < off) red[threadIdx.x] += red[threadIdx.x + off];
        __syncthreads();
    }
    const float scale = g[o] / sqrtf(red[0]);
    for (int k = threadIdx.x; k < K; k += 256) {
        float val = scale * v[(size_t)o * K + k];
        if (TR) w[(size_t)k * LD + o] = val;
        else    w[(size_t)o * K + k] = val;
    }
}

// ---------------- conv1 (2->8, 128x128 -> 32x32) fused with CUBA -----------
__global__ __launch_bounds__(256) void conv1_cuba(const float* __restrict__ x,
                                                  const float* __restrict__ w1T,
                                                  float* __restrict__ s1) {
    __shared__ float lds[4][8][68];
    const int wid = threadIdx.x >> 6, t = threadIdx.x & 63;
    const int task = blockIdx.x * 4 + wid;  // 0..16383
    const int spi = task & 1023, b = task >> 10;
    const int oy = spi >> 5, ox = spi & 31;

    float a0=0,a1=0,a2=0,a3=0,a4=0,a5=0,a6=0,a7=0;
    const float* xb = x + (size_t)b * 2 * 128 * 128 * TT + t;

    if (oy >= 1 && ox >= 1) {
        const float* xq = xb + ((size_t)((oy * 4 - 1) * 128 + ox * 4 - 1)) * TT;
        float xv[50];
#pragma unroll
        for (int ci = 0; ci < 2; ci++)
#pragma unroll
            for (int ky = 0; ky < 5; ky++)
#pragma unroll
                for (int kx = 0; kx < 5; kx++)
                    xv[ci * 25 + ky * 5 + kx] =
                        xq[((size_t)(ci * 16384 + ky * 128 + kx)) * TT];
#pragma unroll
        for (int k = 0; k < 50; k++) {
            const float4* wp = (const float4*)(w1T + k * 8);
            const float4 wA = wp[0], wB = wp[1];
            const float xvk = xv[k];
            a0 = fmaf(wA.x, xvk, a0); a1 = fmaf(wA.y, xvk, a1);
            a2 = fmaf(wA.z, xvk, a2); a3 = fmaf(wA.w, xvk, a3);
            a4 = fmaf(wB.x, xvk, a4); a5 = fmaf(wB.y, xvk, a5);
            a6 = fmaf(wB.z, xvk, a6); a7 = fmaf(wB.w, xvk, a7);
        }
    } else {
        for (int ci = 0; ci < 2; ci++) {
#pragma unroll
            for (int ky = 0; ky < 5; ky++) {
                const int iy = oy * 4 + ky - 1;
                if (iy < 0 || iy >= 128) continue;
#pragma unroll
                for (int kx = 0; kx < 5; kx++) {
                    const int ix = ox * 4 + kx - 1;
                    if (ix < 0 || ix >= 128) continue;
                    const float xvk = xb[((size_t)((ci * 128 + iy) * 128 + ix)) * TT];
                    const float4* wp = (const float4*)(w1T + (ci * 25 + ky * 5 + kx) * 8);
                    const float4 wA = wp[0], wB = wp[1];
                    a0 = fmaf(wA.x, xvk, a0); a1 = fmaf(wA.y, xvk, a1);
                    a2 = fmaf(wA.z, xvk, a2); a3 = fmaf(wA.w, xvk, a3);
                    a4 = fmaf(wB.x, xvk, a4); a5 = fmaf(wB.y, xvk, a5);
                    a6 = fmaf(wB.z, xvk, a6); a7 = fmaf(wB.w, xvk, a7);
                }
            }
        }
    }
    lds[wid][0][t] = a0; lds[wid][1][t] = a1; lds[wid][2][t] = a2; lds[wid][3][t] = a3;
    lds[wid][4][t] = a4; lds[wid][5][t] = a5; lds[wid][6][t] = a6; lds[wid][7][t] = a7;
    __syncthreads();
    if (t < 8) {
        const int ch = t;
        float4 r[16];
#pragma unroll
        for (int j = 0; j < 16; j++) r[j] = *(const float4*)&lds[wid][ch][j * 4];
        float c = 0.f, v = 0.f;
#pragma unroll
        for (int j = 0; j < 16; j++) scan4(c, v, r[j]);
        float4* op = (float4*)(s1 + (((size_t)b * 8 + ch) * 1024 + spi) * TT);
#pragma unroll
        for (int j = 0; j < 16; j++) op[j] = r[j];
    }
}

// ---------------- conv2 z (8->32, 32x32 -> 8x8), t-parallel, 16 o/wave -----
__global__ __launch_bounds__(256) void conv2_z(const float* __restrict__ s1,
                                               const float* __restrict__ w2T,
                                               float* __restrict__ z2) {
    const int wid = threadIdx.x >> 6, t = threadIdx.x & 63;
    const int task = blockIdx.x * 4 + wid;  // 0..2047
    const int og = task & 1;
    const int spi = (task >> 1) & 63;
    const int b = task >> 7;
    const int oy = spi >> 3, ox = spi & 7;

    float a[16];
#pragma unroll
    for (int j = 0; j < 16; j++) a[j] = 0.f;
    const float* xb = s1 + (size_t)b * 8 * 32 * 32 * TT + t;

    if (oy >= 1 && ox >= 1) {
        const float* xq = xb + ((size_t)((oy * 4 - 1) * 32 + ox * 4 - 1)) * TT;
        for (int cp = 0; cp < 4; cp++) {  // ci pairs: (0,1),(2,3),(4,5),(6,7)
            float xv[50];
#pragma unroll
            for (int cc = 0; cc < 2; cc++)
#pragma unroll
                for (int ky = 0; ky < 5; ky++)
#pragma unroll
                    for (int kx = 0; kx < 5; kx++)
                        xv[cc * 25 + ky * 5 + kx] =
                            xq[((size_t)(((cp * 2 + cc) * 1024) + ky * 32 + kx)) * TT];
#pragma unroll
            for (int k = 0; k < 50; k++) {
                const int row = (cp * 2 + (k >= 25 ? 1 : 0)) * 25 + (k >= 25 ? k - 25 : k);
                const float4* wp = (const float4*)(w2T + row * 32 + og * 16);
                const float4 w0 = wp[0], w1 = wp[1], w2 = wp[2], w3 = wp[3];
                const float xvk = xv[k];
                a[0]  = fmaf(w0.x, xvk, a[0]);  a[1]  = fmaf(w0.y, xvk, a[1]);
                a[2]  = fmaf(w0.z, xvk, a[2]);  a[3]  = fmaf(w0.w, xvk, a[3]);
                a[4]  = fmaf(w1.x, xvk, a[4]);  a[5]  = fmaf(w1.y, xvk, a[5]);
                a[6]  = fmaf(w1.z, xvk, a[6]);  a[7]  = fmaf(w1.w, xvk, a[7]);
                a[8]  = fmaf(w2.x, xvk, a[8]);  a[9]  = fmaf(w2.y, xvk, a[9]);
                a[10] = fmaf(w2.z, xvk, a[10]); a[11] = fmaf(w2.w, xvk, a[11]);
                a[12] = fmaf(w3.x, xvk, a[12]); a[13] = fmaf(w3.y, xvk, a[13]);
                a[14] = fmaf(w3.z, xvk, a[14]); a[15] = fmaf(w3.w, xvk, a[15]);
            }
        }
    } else {
        for (int ci = 0; ci < 8; ci++) {
#pragma unroll
            for (int ky = 0; ky < 5; ky++) {
                const int iy = oy * 4 + ky - 1;
                if (iy < 0 || iy >= 32) continue;
#pragma unroll
                for (int kx = 0; kx < 5; kx++) {
                    const int ix = ox * 4 + kx - 1;
                    if (ix < 0 || ix >= 32) continue;
                    const float xvk = xb[((size_t)((ci * 32 + iy) * 32 + ix)) * TT];
                    const float4* wp =
                        (const float4*)(w2T + (ci * 25 + ky * 5 + kx) * 32 + og * 16);
                    const float4 w0 = wp[0], w1 = wp[1], w2 = wp[2], w3 = wp[3];
                    a[0]  = fmaf(w0.x, xvk, a[0]);  a[1]  = fmaf(w0.y, xvk, a[1]);
                    a[2]  = fmaf(w0.z, xvk, a[2]);  a[3]  = fmaf(w0.w, xvk, a[3]);
                    a[4]  = fmaf(w1.x, xvk, a[4]);  a[5]  = fmaf(w1.y, xvk, a[5]);
                    a[6]  = fmaf(w1.z, xvk, a[6]);  a[7]  = fmaf(w1.w, xvk, a[7]);
                    a[8]  = fmaf(w2.x, xvk, a[8]);  a[9]  = fmaf(w2.y, xvk, a[9]);
                    a[10] = fmaf(w2.z, xvk, a[10]); a[11] = fmaf(w2.w, xvk, a[11]);
                    a[12] = fmaf(w3.x, xvk, a[12]); a[13] = fmaf(w3.y, xvk, a[13]);
                    a[14] = fmaf(w3.z, xvk, a[14]); a[15] = fmaf(w3.w, xvk, a[15]);
                }
            }
        }
    }
    float* zb = z2 + (((size_t)b * 32 + og * 16) * 64 + spi) * TT + t;
#pragma unroll
    for (int j = 0; j < 16; j++) zb[(size_t)j * 64 * TT] = a[j];
}

// ---------------- conv3 z (32->64, 8x8 -> 2x2), ci-split + batched taps -----
// Block = (b,spi,og); 4 waves each own 8 ci (ci = wid*8..wid*8+7, original
// order within the slice). Per ci, all valid taps are loaded into registers
// branch-free (spi is wave-uniform -> compile-time guards via template), then
// the FMA chain runs in the original ky->kx order. Deterministic fixed-order
// LDS reduce across the 4 waves (w0+w1+w2+w3).
template <int OY, int OX>
__device__ __forceinline__ void conv3_acc(const float* __restrict__ xb,
                                          const float* __restrict__ wTo,
                                          int wid, float* __restrict__ acc) {
    constexpr int KY0 = (OY == 0) ? 1 : 0;
    constexpr int KX0 = (OX == 0) ? 1 : 0;
    constexpr int NKY = 5 - KY0;
    constexpr int NKX = 5 - KX0;
    for (int c8 = 0; c8 < 8; c8++) {
        const int ci = wid * 8 + c8;
        float xv[NKY * NKX];
#pragma unroll
        for (int ky = KY0; ky < 5; ky++) {
#pragma unroll
            for (int kx = KX0; kx < 5; kx++) {
                const int iy = OY * 4 + ky - 1;
                const int ix = OX * 4 + kx - 1;
                xv[(ky - KY0) * NKX + (kx - KX0)] =
                    xb[((size_t)((ci * 8 + iy) * 8 + ix)) * TT];
            }
        }
#pragma unroll
        for (int ky = KY0; ky < 5; ky++) {
#pragma unroll
            for (int kx = KX0; kx < 5; kx++) {
                const float xvk = xv[(ky - KY0) * NKX + (kx - KX0)];
                const float4* wp = (const float4*)(wTo + (ci * 25 + ky * 5 + kx) * 64);
                const float4 wA = wp[0], wB = wp[1];
                acc[0] = fmaf(wA.x, xvk, acc[0]); acc[1] = fmaf(wA.y, xvk, acc[1]);
                acc[2] = fmaf(wA.z, xvk, acc[2]); acc[3] = fmaf(wA.w, xvk, acc[3]);
                acc[4] = fmaf(wB.x, xvk, acc[4]); acc[5] = fmaf(wB.y, xvk, acc[5]);
                acc[6] = fmaf(wB.z, xvk, acc[6]); acc[7] = fmaf(wB.w, xvk, acc[7]);
            }
        }
    }
}

__global__ __launch_bounds__(256) void conv3_z(const float* __restrict__ s2,
                                               const float* __restrict__ wT,
                                               float* __restrict__ z3) {
    __shared__ float red[4][8][64];
    const int wid = threadIdx.x >> 6, t = threadIdx.x & 63;
    const int og = blockIdx.x & 7;
    const int spi = (blockIdx.x >> 3) & 3;
    const int b = blockIdx.x >> 5;

    float acc[8];
#pragma unroll
    for (int j = 0; j < 8; j++) acc[j] = 0.f;
    const float* xb = s2 + (size_t)b * 32 * 8 * 8 * TT + t;
    const float* wTo = wT + og * 8;

    switch (spi) {
        case 0: conv3_acc<0, 0>(xb, wTo, wid, acc); break;
        case 1: conv3_acc<0, 1>(xb, wTo, wid, acc); break;
        case 2: conv3_acc<1, 0>(xb, wTo, wid, acc); break;
        default: conv3_acc<1, 1>(xb, wTo, wid, acc); break;
    }
#pragma unroll
    for (int j = 0; j < 8; j++) red[wid][j][t] = acc[j];
    __syncthreads();
    if (wid == 0) {
        float* zb = z3 + ((size_t)b * 256 + (size_t)og * 32 + spi) * TT + t;
#pragma unroll
        for (int j = 0; j < 8; j++) {
            const float s = ((red[0][j][t] + red[1][j][t]) + red[2][j][t]) + red[3][j][t];
            zb[(size_t)j * 4 * TT] = s;
        }
    }
}

// ---------------- generic de-fused CUBA scan: z (N,64) -> spikes (N,64) -----
__global__ __launch_bounds__(256) void scan_s(const float* __restrict__ z,
                                              float* __restrict__ s, int N) {
    const int n = blockIdx.x * 256 + threadIdx.x;
    if (n >= N) return;
    const float4* zp = (const float4*)(z + (size_t)n * TT);
    float4* sp = (float4*)(s + (size_t)n * TT);
    float c = 0.f, v = 0.f;
    for (int tc = 0; tc < 4; tc++) {
        float4 a0 = zp[tc * 4 + 0], a1 = zp[tc * 4 + 1];
        float4 a2 = zp[tc * 4 + 2], a3 = zp[tc * 4 + 3];
        scan4(c, v, a0); scan4(c, v, a1); scan4(c, v, a2); scan4(c, v, a3);
        sp[tc * 4 + 0] = a0; sp[tc * 4 + 1] = a1;
        sp[tc * 4 + 2] = a2; sp[tc * 4 + 3] = a3;
    }
}

// ---------------- dense1 z (256 -> 2056), t-parallel, 16 o/wave -------------
__global__ __launch_bounds__(256) void dense1_z(const float* __restrict__ s3,
                                                const float* __restrict__ wT,
                                                float* __restrict__ zd) {
    const int wid = threadIdx.x >> 6, t = threadIdx.x & 63;
    const int task = blockIdx.x * 4 + wid;  // 0..2063
    const int b = task / 129;
    const int og = task - b * 129;
    const int o0 = og * 16;

    float a[16];
#pragma unroll
    for (int j = 0; j < 16; j++) a[j] = 0.f;
    const float* ab = s3 + (size_t)b * 256 * TT + t;

#pragma unroll 4
    for (int i = 0; i < 256; i++) {
        const float av = ab[(size_t)i * TT];
        const float4* wp = (const float4*)(wT + (size_t)i * 2056 + o0);
        const float4 w0 = wp[0], w1 = wp[1], w2 = wp[2], w3 = wp[3];
        a[0]  = fmaf(w0.x, av, a[0]);  a[1]  = fmaf(w0.y, av, a[1]);
        a[2]  = fmaf(w0.z, av, a[2]);  a[3]  = fmaf(w0.w, av, a[3]);
        a[4]  = fmaf(w1.x, av, a[4]);  a[5]  = fmaf(w1.y, av, a[5]);
        a[6]  = fmaf(w1.z, av, a[6]);  a[7]  = fmaf(w1.w, av, a[7]);
        a[8]  = fmaf(w2.x, av, a[8]);  a[9]  = fmaf(w2.y, av, a[9]);
        a[10] = fmaf(w2.z, av, a[10]); a[11] = fmaf(w2.w, av, a[11]);
        a[12] = fmaf(w3.x, av, a[12]); a[13] = fmaf(w3.y, av, a[13]);
        a[14] = fmaf(w3.z, av, a[14]); a[15] = fmaf(w3.w, av, a[15]);
    }
    float* zb = zd + ((size_t)b * 2056 + o0) * TT + t;
#pragma unroll
    for (int j = 0; j < 16; j++)
        if (o0 + j < 2056) zb[(size_t)j * TT] = a[j];
}

// ---------------- dense2 stage 1: split-K partial sums ----------------------
__global__ __launch_bounds__(256) void dense2_part(const float* __restrict__ s4,
                                                   const float* __restrict__ wP,
                                                   float* __restrict__ z4p) {
    __shared__ float red[4][11][64];
    const int sp = blockIdx.x, b = blockIdx.y;
    const int w = threadIdx.x >> 6, t = threadIdx.x & 63;
    const int i0 = sp * 257, iend = i0 + 257;  // 2056 = 8*257
    const float* src = s4 + (size_t)b * 2056 * TT + t;

    float acc[11];
#pragma unroll
    for (int j = 0; j < 11; j++) acc[j] = 0.f;

    for (int i = i0 + w; i < iend; i += 4) {
        const float xv = src[(size_t)i * TT];
        const float4* wp = (const float4*)(wP + (size_t)i * 12);
        const float4 w0 = wp[0], w1 = wp[1], w2 = wp[2];
        acc[0]  = fmaf(w0.x, xv, acc[0]);  acc[1]  = fmaf(w0.y, xv, acc[1]);
        acc[2]  = fmaf(w0.z, xv, acc[2]);  acc[3]  = fmaf(w0.w, xv, acc[3]);
        acc[4]  = fmaf(w1.x, xv, acc[4]);  acc[5]  = fmaf(w1.y, xv, acc[5]);
        acc[6]  = fmaf(w1.z, xv, acc[6]);  acc[7]  = fmaf(w1.w, xv, acc[7]);
        acc[8]  = fmaf(w2.x, xv, acc[8]);  acc[9]  = fmaf(w2.y, xv, acc[9]);
        acc[10] = fmaf(w2.z, xv, acc[10]);
    }
#pragma unroll
    for (int j = 0; j < 11; j++) red[w][j][t] = acc[j];
    __syncthreads();
    if (w == 0) {
#pragma unroll
        for (int j = 0; j < 11; j++) {
            const float s = red[0][j][t] + red[1][j][t] + red[2][j][t] + red[3][j][t];
            z4p[(((size_t)b * 8 + sp) * 11 + j) * TT + t] = s;
        }
    }
}

// ---------------- dense2 stage 2: fixed-order reduce + final CUBA scan ------
__global__ __launch_bounds__(256) void dense2_scan(const float* __restrict__ z4p,
                                                   float* __restrict__ out) {
    __shared__ float z[11][64];
    const int b = blockIdx.x;
    for (int idx = threadIdx.x; idx < 11 * 64; idx += 256) {
        const int o = idx >> 6, t = idx & 63;
        float s = 0.f;
#pragma unroll
        for (int sp = 0; sp < 8; sp++)
            s += z4p[(((size_t)b * 8 + sp) * 11 + o) * TT + t];
        z[o][t] = s;
    }
    __syncthreads();
    if (threadIdx.x < 11) {
        const int o = threadIdx.x;
        float c = 0.f, v = 0.f;
        float* op = out + ((size_t)b * 11 + o) * TT;
#pragma unroll
        for (int t = 0; t < TT; t++) {
            float zz = z[o][t];
            scanc(c, v, zz);
            op[t] = zz;
        }
    }
}

extern "C" void kernel_launch(void* const* d_in, const int* in_sizes, int n_in,
                              void* d_out, int out_size, void* d_ws, size_t ws_size,
                              hipStream_t stream) {
    const float* x   = (const float*)d_in[0];
    const float* c1v = (const float*)d_in[1];  const float* c1g = (const float*)d_in[2];
    const float* c2v = (const float*)d_in[3];  const float* c2g = (const float*)d_in[4];
    const float* c3v = (const float*)d_in[5];  const float* c3g = (const float*)d_in[6];
    const float* d1v = (const float*)d_in[7];  const float* d1g = (const float*)d_in[8];
    const float* d2v = (const float*)d_in[9];  const float* d2g = (const float*)d_in[10];

    float* ws = (float*)d_ws;
    // weight region
    float* w1T  = ws + 0;        // (50,8)     = 400
    float* w2T  = ws + 400;      // (200,32)   = 6400
    float* w3T  = ws + 6800;     // (800,64)   = 51200
    float* wd1T = ws + 58000;    // (256,2056) = 526336
    float* wd2P = ws + 584336;   // (2056,12) padded = 24672
    // region A (8,388,608 floats) and region B (4,194,304 floats), multiplexed
    float* A = ws + 609008;
    float* B = A + 8388608;
    float* s1  = A;              // conv1 spikes (b,8,32,32,t)
    float* s3  = A;              // dense-in spikes (b,256,t)    [after s1 dead]
    float* s4  = A + 262144;     // dense1 spikes (b,2056,t)
    float* z2  = B;              // conv2 pre-act (b,32,64,t)
    float* s2  = B + 2097152;    // conv2 spikes
    float* z3  = B;              // conv3 pre-act (b,256,t)      [after z2 dead]
    float* zd1 = B;              // dense1 pre-act (b,2056,t)    [after z3,s2 dead]
    float* z4p = B;              // dense2 partials (b,8,11,t)   [after zd1 dead]
    (void)ws_size; (void)in_sizes; (void)n_in; (void)out_size;

    // normalized weights (transposed (K,O) where the z-kernels want it)
    wnorm<true> <<<dim3(8),    dim3(256), 0, stream>>>(c1v, c1g, w1T, 8, 50, 8);
    wnorm<true> <<<dim3(32),   dim3(256), 0, stream>>>(c2v, c2g, w2T, 32, 200, 32);
    wnorm<true> <<<dim3(64),   dim3(256), 0, stream>>>(c3v, c3g, w3T, 64, 800, 64);
    wnorm<true> <<<dim3(2056), dim3(256), 0, stream>>>(d1v, d1g, wd1T, 2056, 256, 2056);
    wnorm<true> <<<dim3(11),   dim3(256), 0, stream>>>(d2v, d2g, wd2P, 11, 2056, 12);

    // pipeline
    conv1_cuba <<<dim3(4096), dim3(256), 0, stream>>>(x, w1T, s1);
    conv2_z    <<<dim3(512),  dim3(256), 0, stream>>>(s1, w2T, z2);
    scan_s     <<<dim3(128),  dim3(256), 0, stream>>>(z2, s2, 32768);
    conv3_z    <<<dim3(512),  dim3(256), 0, stream>>>(s2, w3T, z3);
    scan_s     <<<dim3(16),   dim3(256), 0, stream>>>(z3, s3, 4096);
    dense1_z   <<<dim3(516),  dim3(256), 0, stream>>>(s3, wd1T, zd1);
    scan_s     <<<dim3(129),  dim3(256), 0, stream>>>(zd1, s4, 32896);
    dense2_part<<<dim3(8, 16), dim3(256), 0, stream>>>(s4, wd2P, z4p);
    dense2_scan<<<dim3(16),   dim3(256), 0, stream>>>(z4p, (float*)d_out);
}

// Round 7
// 263.933 us; speedup vs baseline: 5.1725x; 1.2577x over previous
//
#include <hip/hip_runtime.h>
#include <cstddef>

#define TT 64  // timesteps

// ---------------- CUBA LIF step helpers ----------------
__device__ __forceinline__ void scanc(float& c, float& v, float& z) {
    c = fmaf(0.7f, c, z);
    v = fmaf(0.75f, v, c);
    float s = (v >= 1.0f) ? 1.0f : 0.0f;
    v = (v >= 1.0f) ? 0.0f : v;
    z = s;
}
__device__ __forceinline__ void scan4(float& c, float& v, float4& a) {
    scanc(c, v, a.x); scanc(c, v, a.y); scanc(c, v, a.z); scanc(c, v, a.w);
}

// ---------------- weight_norm (per output channel) --------------------------
template <bool TR>
__global__ __launch_bounds__(256) void wnorm(const float* __restrict__ v,
                                             const float* __restrict__ g,
                                             float* __restrict__ w, int O, int K,
                                             int LD) {
    __shared__ float red[256];
    const int o = blockIdx.x;
    float s = 0.f;
    for (int k = threadIdx.x; k < K; k += 256) {
        float x = v[(size_t)o * K + k];
        s += x * x;
    }
    red[threadIdx.x] = s;
    __syncthreads();
    for (int off = 128; off > 0; off >>= 1) {
        if (threadIdx.x < off) red[threadIdx.x] += red[threadIdx.x + off];
        __syncthreads();
    }
    const float scale = g[o] / sqrtf(red[0]);
    for (int k = threadIdx.x; k < K; k += 256) {
        float val = scale * v[(size_t)o * K + k];
        if (TR) w[(size_t)k * LD + o] = val;
        else    w[(size_t)o * K + k] = val;
    }
}

// ---------------- conv1 (2->8, 128x128 -> 32x32) fused with CUBA -----------
__global__ __launch_bounds__(256) void conv1_cuba(const float* __restrict__ x,
                                                  const float* __restrict__ w1T,
                                                  float* __restrict__ s1) {
    __shared__ float lds[4][8][68];
    const int wid = threadIdx.x >> 6, t = threadIdx.x & 63;
    const int task = blockIdx.x * 4 + wid;  // 0..16383
    const int spi = task & 1023, b = task >> 10;
    const int oy = spi >> 5, ox = spi & 31;

    float a0=0,a1=0,a2=0,a3=0,a4=0,a5=0,a6=0,a7=0;
    const float* xb = x + (size_t)b * 2 * 128 * 128 * TT + t;

    if (oy >= 1 && ox >= 1) {
        const float* xq = xb + ((size_t)((oy * 4 - 1) * 128 + ox * 4 - 1)) * TT;
        float xv[50];
#pragma unroll
        for (int ci = 0; ci < 2; ci++)
#pragma unroll
            for (int ky = 0; ky < 5; ky++)
#pragma unroll
                for (int kx = 0; kx < 5; kx++)
                    xv[ci * 25 + ky * 5 + kx] =
                        xq[((size_t)(ci * 16384 + ky * 128 + kx)) * TT];
#pragma unroll
        for (int k = 0; k < 50; k++) {
            const float4* wp = (const float4*)(w1T + k * 8);
            const float4 wA = wp[0], wB = wp[1];
            const float xvk = xv[k];
            a0 = fmaf(wA.x, xvk, a0); a1 = fmaf(wA.y, xvk, a1);
            a2 = fmaf(wA.z, xvk, a2); a3 = fmaf(wA.w, xvk, a3);
            a4 = fmaf(wB.x, xvk, a4); a5 = fmaf(wB.y, xvk, a5);
            a6 = fmaf(wB.z, xvk, a6); a7 = fmaf(wB.w, xvk, a7);
        }
    } else {
        for (int ci = 0; ci < 2; ci++) {
#pragma unroll
            for (int ky = 0; ky < 5; ky++) {
                const int iy = oy * 4 + ky - 1;
                if (iy < 0 || iy >= 128) continue;
#pragma unroll
                for (int kx = 0; kx < 5; kx++) {
                    const int ix = ox * 4 + kx - 1;
                    if (ix < 0 || ix >= 128) continue;
                    const float xvk = xb[((size_t)((ci * 128 + iy) * 128 + ix)) * TT];
                    const float4* wp = (const float4*)(w1T + (ci * 25 + ky * 5 + kx) * 8);
                    const float4 wA = wp[0], wB = wp[1];
                    a0 = fmaf(wA.x, xvk, a0); a1 = fmaf(wA.y, xvk, a1);
                    a2 = fmaf(wA.z, xvk, a2); a3 = fmaf(wA.w, xvk, a3);
                    a4 = fmaf(wB.x, xvk, a4); a5 = fmaf(wB.y, xvk, a5);
                    a6 = fmaf(wB.z, xvk, a6); a7 = fmaf(wB.w, xvk, a7);
                }
            }
        }
    }
    lds[wid][0][t] = a0; lds[wid][1][t] = a1; lds[wid][2][t] = a2; lds[wid][3][t] = a3;
    lds[wid][4][t] = a4; lds[wid][5][t] = a5; lds[wid][6][t] = a6; lds[wid][7][t] = a7;
    __syncthreads();
    if (t < 8) {
        const int ch = t;
        float4 r[16];
#pragma unroll
        for (int j = 0; j < 16; j++) r[j] = *(const float4*)&lds[wid][ch][j * 4];
        float c = 0.f, v = 0.f;
#pragma unroll
        for (int j = 0; j < 16; j++) scan4(c, v, r[j]);
        float4* op = (float4*)(s1 + (((size_t)b * 8 + ch) * 1024 + spi) * TT);
#pragma unroll
        for (int j = 0; j < 16; j++) op[j] = r[j];
    }
}

// ---------------- conv2 z (8->32, 32x32 -> 8x8), t-parallel, 16 o/wave -----
__global__ __launch_bounds__(256) void conv2_z(const float* __restrict__ s1,
                                               const float* __restrict__ w2T,
                                               float* __restrict__ z2) {
    const int wid = threadIdx.x >> 6, t = threadIdx.x & 63;
    const int task = blockIdx.x * 4 + wid;  // 0..2047
    const int og = task & 1;
    const int spi = (task >> 1) & 63;
    const int b = task >> 7;
    const int oy = spi >> 3, ox = spi & 7;

    float a[16];
#pragma unroll
    for (int j = 0; j < 16; j++) a[j] = 0.f;
    const float* xb = s1 + (size_t)b * 8 * 32 * 32 * TT + t;

    if (oy >= 1 && ox >= 1) {
        const float* xq = xb + ((size_t)((oy * 4 - 1) * 32 + ox * 4 - 1)) * TT;
        for (int cp = 0; cp < 4; cp++) {  // ci pairs: (0,1),(2,3),(4,5),(6,7)
            float xv[50];
#pragma unroll
            for (int cc = 0; cc < 2; cc++)
#pragma unroll
                for (int ky = 0; ky < 5; ky++)
#pragma unroll
                    for (int kx = 0; kx < 5; kx++)
                        xv[cc * 25 + ky * 5 + kx] =
                            xq[((size_t)(((cp * 2 + cc) * 1024) + ky * 32 + kx)) * TT];
#pragma unroll
            for (int k = 0; k < 50; k++) {
                const int row = (cp * 2 + (k >= 25 ? 1 : 0)) * 25 + (k >= 25 ? k - 25 : k);
                const float4* wp = (const float4*)(w2T + row * 32 + og * 16);
                const float4 w0 = wp[0], w1 = wp[1], w2 = wp[2], w3 = wp[3];
                const float xvk = xv[k];
                a[0]  = fmaf(w0.x, xvk, a[0]);  a[1]  = fmaf(w0.y, xvk, a[1]);
                a[2]  = fmaf(w0.z, xvk, a[2]);  a[3]  = fmaf(w0.w, xvk, a[3]);
                a[4]  = fmaf(w1.x, xvk, a[4]);  a[5]  = fmaf(w1.y, xvk, a[5]);
                a[6]  = fmaf(w1.z, xvk, a[6]);  a[7]  = fmaf(w1.w, xvk, a[7]);
                a[8]  = fmaf(w2.x, xvk, a[8]);  a[9]  = fmaf(w2.y, xvk, a[9]);
                a[10] = fmaf(w2.z, xvk, a[10]); a[11] = fmaf(w2.w, xvk, a[11]);
                a[12] = fmaf(w3.x, xvk, a[12]); a[13] = fmaf(w3.y, xvk, a[13]);
                a[14] = fmaf(w3.z, xvk, a[14]); a[15] = fmaf(w3.w, xvk, a[15]);
            }
        }
    } else {
        for (int ci = 0; ci < 8; ci++) {
#pragma unroll
            for (int ky = 0; ky < 5; ky++) {
                const int iy = oy * 4 + ky - 1;
                if (iy < 0 || iy >= 32) continue;
#pragma unroll
                for (int kx = 0; kx < 5; kx++) {
                    const int ix = ox * 4 + kx - 1;
                    if (ix < 0 || ix >= 32) continue;
                    const float xvk = xb[((size_t)((ci * 32 + iy) * 32 + ix)) * TT];
                    const float4* wp =
                        (const float4*)(w2T + (ci * 25 + ky * 5 + kx) * 32 + og * 16);
                    const float4 w0 = wp[0], w1 = wp[1], w2 = wp[2], w3 = wp[3];
                    a[0]  = fmaf(w0.x, xvk, a[0]);  a[1]  = fmaf(w0.y, xvk, a[1]);
                    a[2]  = fmaf(w0.z, xvk, a[2]);  a[3]  = fmaf(w0.w, xvk, a[3]);
                    a[4]  = fmaf(w1.x, xvk, a[4]);  a[5]  = fmaf(w1.y, xvk, a[5]);
                    a[6]  = fmaf(w1.z, xvk, a[6]);  a[7]  = fmaf(w1.w, xvk, a[7]);
                    a[8]  = fmaf(w2.x, xvk, a[8]);  a[9]  = fmaf(w2.y, xvk, a[9]);
                    a[10] = fmaf(w2.z, xvk, a[10]); a[11] = fmaf(w2.w, xvk, a[11]);
                    a[12] = fmaf(w3.x, xvk, a[12]); a[13] = fmaf(w3.y, xvk, a[13]);
                    a[14] = fmaf(w3.z, xvk, a[14]); a[15] = fmaf(w3.w, xvk, a[15]);
                }
            }
        }
    }
    float* zb = z2 + (((size_t)b * 32 + og * 16) * 64 + spi) * TT + t;
#pragma unroll
    for (int j = 0; j < 16; j++) zb[(size_t)j * 64 * TT] = a[j];
}

// ---------------- conv3 z (32->64, 8x8 -> 2x2), ci-split + batched taps -----
template <int OY, int OX>
__device__ __forceinline__ void conv3_acc(const float* __restrict__ xb,
                                          const float* __restrict__ wTo,
                                          int wid, float* __restrict__ acc) {
    constexpr int KY0 = (OY == 0) ? 1 : 0;
    constexpr int KX0 = (OX == 0) ? 1 : 0;
    constexpr int NKY = 5 - KY0;
    constexpr int NKX = 5 - KX0;
    for (int c8 = 0; c8 < 8; c8++) {
        const int ci = wid * 8 + c8;
        float xv[NKY * NKX];
#pragma unroll
        for (int ky = KY0; ky < 5; ky++) {
#pragma unroll
            for (int kx = KX0; kx < 5; kx++) {
                const int iy = OY * 4 + ky - 1;
                const int ix = OX * 4 + kx - 1;
                xv[(ky - KY0) * NKX + (kx - KX0)] =
                    xb[((size_t)((ci * 8 + iy) * 8 + ix)) * TT];
            }
        }
#pragma unroll
        for (int ky = KY0; ky < 5; ky++) {
#pragma unroll
            for (int kx = KX0; kx < 5; kx++) {
                const float xvk = xv[(ky - KY0) * NKX + (kx - KX0)];
                const float4* wp = (const float4*)(wTo + (ci * 25 + ky * 5 + kx) * 64);
                const float4 wA = wp[0], wB = wp[1];
                acc[0] = fmaf(wA.x, xvk, acc[0]); acc[1] = fmaf(wA.y, xvk, acc[1]);
                acc[2] = fmaf(wA.z, xvk, acc[2]); acc[3] = fmaf(wA.w, xvk, acc[3]);
                acc[4] = fmaf(wB.x, xvk, acc[4]); acc[5] = fmaf(wB.y, xvk, acc[5]);
                acc[6] = fmaf(wB.z, xvk, acc[6]); acc[7] = fmaf(wB.w, xvk, acc[7]);
            }
        }
    }
}

__global__ __launch_bounds__(256) void conv3_z(const float* __restrict__ s2,
                                               const float* __restrict__ wT,
                                               float* __restrict__ z3) {
    __shared__ float red[4][8][64];
    const int wid = threadIdx.x >> 6, t = threadIdx.x & 63;
    const int og = blockIdx.x & 7;
    const int spi = (blockIdx.x >> 3) & 3;
    const int b = blockIdx.x >> 5;

    float acc[8];
#pragma unroll
    for (int j = 0; j < 8; j++) acc[j] = 0.f;
    const float* xb = s2 + (size_t)b * 32 * 8 * 8 * TT + t;
    const float* wTo = wT + og * 8;

    switch (spi) {
        case 0: conv3_acc<0, 0>(xb, wTo, wid, acc); break;
        case 1: conv3_acc<0, 1>(xb, wTo, wid, acc); break;
        case 2: conv3_acc<1, 0>(xb, wTo, wid, acc); break;
        default: conv3_acc<1, 1>(xb, wTo, wid, acc); break;
    }
#pragma unroll
    for (int j = 0; j < 8; j++) red[wid][j][t] = acc[j];
    __syncthreads();
    if (wid == 0) {
        float* zb = z3 + ((size_t)b * 256 + (size_t)og * 32 + spi) * TT + t;
#pragma unroll
        for (int j = 0; j < 8; j++) {
            const float s = ((red[0][j][t] + red[1][j][t]) + red[2][j][t]) + red[3][j][t];
            zb[(size_t)j * 4 * TT] = s;
        }
    }
}

// ---------------- generic de-fused CUBA scan: z (N,64) -> spikes (N,64) -----
__global__ __launch_bounds__(256) void scan_s(const float* __restrict__ z,
                                              float* __restrict__ s, int N) {
    const int n = blockIdx.x * 256 + threadIdx.x;
    if (n >= N) return;
    const float4* zp = (const float4*)(z + (size_t)n * TT);
    float4* sp = (float4*)(s + (size_t)n * TT);
    float c = 0.f, v = 0.f;
    for (int tc = 0; tc < 4; tc++) {
        float4 a0 = zp[tc * 4 + 0], a1 = zp[tc * 4 + 1];
        float4 a2 = zp[tc * 4 + 2], a3 = zp[tc * 4 + 3];
        scan4(c, v, a0); scan4(c, v, a1); scan4(c, v, a2); scan4(c, v, a3);
        sp[tc * 4 + 0] = a0; sp[tc * 4 + 1] = a1;
        sp[tc * 4 + 2] = a2; sp[tc * 4 + 3] = a3;
    }
}

// ---------------- dense1 z (256 -> 2056), 8 o/wave, scalar weight loads -----
// Weights in ORIGINAL (O,K)=(2056,256) layout: per-o rows contiguous. b and o0
// pinned to SGPRs via readfirstlane -> weight addresses provably wave-uniform
// -> s_load on the scalar pipe; VMEM carries only the coalesced activation
// loads. Manual x4 i-unroll: 12 loads in flight, then 32 FMAs in strict
// i-ascending order per accumulator (bit-identical per-o chains).
__global__ __launch_bounds__(256) void dense1_z(const float* __restrict__ s3,
                                                const float* __restrict__ w,
                                                float* __restrict__ zd) {
    const int wid = threadIdx.x >> 6, t = threadIdx.x & 63;
    const int task = blockIdx.x * 4 + wid;  // 0..4111  (16 b x 257 og)
    const int bq = task / 257;
    const int ogq = task - bq * 257;
    const int b = __builtin_amdgcn_readfirstlane(bq);
    const int o0 = __builtin_amdgcn_readfirstlane(ogq * 8);

    float a0=0,a1=0,a2=0,a3=0,a4=0,a5=0,a6=0,a7=0;
    const float* ab = s3 + (size_t)b * 256 * TT + t;
    const float* r0 = w + (size_t)(o0 + 0) * 256;
    const float* r1 = w + (size_t)(o0 + 1) * 256;
    const float* r2 = w + (size_t)(o0 + 2) * 256;
    const float* r3 = w + (size_t)(o0 + 3) * 256;
    const float* r4 = w + (size_t)(o0 + 4) * 256;
    const float* r5 = w + (size_t)(o0 + 5) * 256;
    const float* r6 = w + (size_t)(o0 + 6) * 256;
    const float* r7 = w + (size_t)(o0 + 7) * 256;

#pragma unroll 2
    for (int i = 0; i < 256; i += 4) {
        const float av0 = ab[(size_t)(i + 0) * TT];
        const float av1 = ab[(size_t)(i + 1) * TT];
        const float av2 = ab[(size_t)(i + 2) * TT];
        const float av3 = ab[(size_t)(i + 3) * TT];
        const float4 q0 = *(const float4*)(r0 + i);
        const float4 q1 = *(const float4*)(r1 + i);
        const float4 q2 = *(const float4*)(r2 + i);
        const float4 q3 = *(const float4*)(r3 + i);
        const float4 q4 = *(const float4*)(r4 + i);
        const float4 q5 = *(const float4*)(r5 + i);
        const float4 q6 = *(const float4*)(r6 + i);
        const float4 q7 = *(const float4*)(r7 + i);
        a0 = fmaf(q0.x, av0, a0); a1 = fmaf(q1.x, av0, a1);
        a2 = fmaf(q2.x, av0, a2); a3 = fmaf(q3.x, av0, a3);
        a4 = fmaf(q4.x, av0, a4); a5 = fmaf(q5.x, av0, a5);
        a6 = fmaf(q6.x, av0, a6); a7 = fmaf(q7.x, av0, a7);
        a0 = fmaf(q0.y, av1, a0); a1 = fmaf(q1.y, av1, a1);
        a2 = fmaf(q2.y, av1, a2); a3 = fmaf(q3.y, av1, a3);
        a4 = fmaf(q4.y, av1, a4); a5 = fmaf(q5.y, av1, a5);
        a6 = fmaf(q6.y, av1, a6); a7 = fmaf(q7.y, av1, a7);
        a0 = fmaf(q0.z, av2, a0); a1 = fmaf(q1.z, av2, a1);
        a2 = fmaf(q2.z, av2, a2); a3 = fmaf(q3.z, av2, a3);
        a4 = fmaf(q4.z, av2, a4); a5 = fmaf(q5.z, av2, a5);
        a6 = fmaf(q6.z, av2, a6); a7 = fmaf(q7.z, av2, a7);
        a0 = fmaf(q0.w, av3, a0); a1 = fmaf(q1.w, av3, a1);
        a2 = fmaf(q2.w, av3, a2); a3 = fmaf(q3.w, av3, a3);
        a4 = fmaf(q4.w, av3, a4); a5 = fmaf(q5.w, av3, a5);
        a6 = fmaf(q6.w, av3, a6); a7 = fmaf(q7.w, av3, a7);
    }
    float* zb = zd + ((size_t)b * 2056 + o0) * TT + t;
    zb[0 * TT] = a0; zb[1 * TT] = a1; zb[2 * TT] = a2; zb[3 * TT] = a3;
    zb[4 * (size_t)TT] = a4; zb[5 * (size_t)TT] = a5;
    zb[6 * (size_t)TT] = a6; zb[7 * (size_t)TT] = a7;
}

// ---------------- dense2 stage 1: split-K partial sums ----------------------
__global__ __launch_bounds__(256) void dense2_part(const float* __restrict__ s4,
                                                   const float* __restrict__ wP,
                                                   float* __restrict__ z4p) {
    __shared__ float red[4][11][64];
    const int sp = blockIdx.x, b = blockIdx.y;
    const int w = threadIdx.x >> 6, t = threadIdx.x & 63;
    const int i0 = sp * 257, iend = i0 + 257;  // 2056 = 8*257
    const float* src = s4 + (size_t)b * 2056 * TT + t;

    float acc[11];
#pragma unroll
    for (int j = 0; j < 11; j++) acc[j] = 0.f;

    for (int i = i0 + w; i < iend; i += 4) {
        const float xv = src[(size_t)i * TT];
        const float4* wp = (const float4*)(wP + (size_t)i * 12);
        const float4 w0 = wp[0], w1 = wp[1], w2 = wp[2];
        acc[0]  = fmaf(w0.x, xv, acc[0]);  acc[1]  = fmaf(w0.y, xv, acc[1]);
        acc[2]  = fmaf(w0.z, xv, acc[2]);  acc[3]  = fmaf(w0.w, xv, acc[3]);
        acc[4]  = fmaf(w1.x, xv, acc[4]);  acc[5]  = fmaf(w1.y, xv, acc[5]);
        acc[6]  = fmaf(w1.z, xv, acc[6]);  acc[7]  = fmaf(w1.w, xv, acc[7]);
        acc[8]  = fmaf(w2.x, xv, acc[8]);  acc[9]  = fmaf(w2.y, xv, acc[9]);
        acc[10] = fmaf(w2.z, xv, acc[10]);
    }
#pragma unroll
    for (int j = 0; j < 11; j++) red[w][j][t] = acc[j];
    __syncthreads();
    if (w == 0) {
#pragma unroll
        for (int j = 0; j < 11; j++) {
            const float s = red[0][j][t] + red[1][j][t] + red[2][j][t] + red[3][j][t];
            z4p[(((size_t)b * 8 + sp) * 11 + j) * TT + t] = s;
        }
    }
}

// ---------------- dense2 stage 2: fixed-order reduce + final CUBA scan ------
__global__ __launch_bounds__(256) void dense2_scan(const float* __restrict__ z4p,
                                                   float* __restrict__ out) {
    __shared__ float z[11][64];
    const int b = blockIdx.x;
    for (int idx = threadIdx.x; idx < 11 * 64; idx += 256) {
        const int o = idx >> 6, t = idx & 63;
        float s = 0.f;
#pragma unroll
        for (int sp = 0; sp < 8; sp++)
            s += z4p[(((size_t)b * 8 + sp) * 11 + o) * TT + t];
        z[o][t] = s;
    }
    __syncthreads();
    if (threadIdx.x < 11) {
        const int o = threadIdx.x;
        float c = 0.f, v = 0.f;
        float* op = out + ((size_t)b * 11 + o) * TT;
#pragma unroll
        for (int t = 0; t < TT; t++) {
            float zz = z[o][t];
            scanc(c, v, zz);
            op[t] = zz;
        }
    }
}

extern "C" void kernel_launch(void* const* d_in, const int* in_sizes, int n_in,
                              void* d_out, int out_size, void* d_ws, size_t ws_size,
                              hipStream_t stream) {
    const float* x   = (const float*)d_in[0];
    const float* c1v = (const float*)d_in[1];  const float* c1g = (const float*)d_in[2];
    const float* c2v = (const float*)d_in[3];  const float* c2g = (const float*)d_in[4];
    const float* c3v = (const float*)d_in[5];  const float* c3g = (const float*)d_in[6];
    const float* d1v = (const float*)d_in[7];  const float* d1g = (const float*)d_in[8];
    const float* d2v = (const float*)d_in[9];  const float* d2g = (const float*)d_in[10];

    float* ws = (float*)d_ws;
    // weight region
    float* w1T  = ws + 0;        // (50,8)     = 400
    float* w2T  = ws + 400;      // (200,32)   = 6400
    float* w3T  = ws + 6800;     // (800,64)   = 51200
    float* wd1  = ws + 58000;    // (2056,256) original layout = 526336
    float* wd2P = ws + 584336;   // (2056,12) padded = 24672
    // region A (8,388,608 floats) and region B (4,194,304 floats), multiplexed
    float* A = ws + 609008;
    float* B = A + 8388608;
    float* s1  = A;              // conv1 spikes (b,8,32,32,t)
    float* s3  = A;              // dense-in spikes (b,256,t)    [after s1 dead]
    float* s4  = A + 262144;     // dense1 spikes (b,2056,t)
    float* z2  = B;              // conv2 pre-act (b,32,64,t)
    float* s2  = B + 2097152;    // conv2 spikes
    float* z3  = B;              // conv3 pre-act (b,256,t)      [after z2 dead]
    float* zd1 = B;              // dense1 pre-act (b,2056,t)    [after z3,s2 dead]
    float* z4p = B;              // dense2 partials (b,8,11,t)   [after zd1 dead]
    (void)ws_size; (void)in_sizes; (void)n_in; (void)out_size;

    // normalized weights
    wnorm<true> <<<dim3(8),    dim3(256), 0, stream>>>(c1v, c1g, w1T, 8, 50, 8);
    wnorm<true> <<<dim3(32),   dim3(256), 0, stream>>>(c2v, c2g, w2T, 32, 200, 32);
    wnorm<true> <<<dim3(64),   dim3(256), 0, stream>>>(c3v, c3g, w3T, 64, 800, 64);
    wnorm<false><<<dim3(2056), dim3(256), 0, stream>>>(d1v, d1g, wd1, 2056, 256, 256);
    wnorm<true> <<<dim3(11),   dim3(256), 0, stream>>>(d2v, d2g, wd2P, 11, 2056, 12);

    // pipeline
    conv1_cuba <<<dim3(4096), dim3(256), 0, stream>>>(x, w1T, s1);
    conv2_z    <<<dim3(512),  dim3(256), 0, stream>>>(s1, w2T, z2);
    scan_s     <<<dim3(128),  dim3(256), 0, stream>>>(z2, s2, 32768);
    conv3_z    <<<dim3(512),  dim3(256), 0, stream>>>(s2, w3T, z3);
    scan_s     <<<dim3(16),   dim3(256), 0, stream>>>(z3, s3, 4096);
    dense1_z   <<<dim3(1028), dim3(256), 0, stream>>>(s3, wd1, zd1);
    scan_s     <<<dim3(129),  dim3(256), 0, stream>>>(zd1, s4, 32896);
    dense2_part<<<dim3(8, 16), dim3(256), 0, stream>>>(s4, wd2P, z4p);
    dense2_scan<<<dim3(16),   dim3(256), 0, stream>>>(z4p, (float*)d_out);
}

// Round 8
// 197.521 us; speedup vs baseline: 6.9116x; 1.3362x over previous
//
#include <hip/hip_runtime.h>
#include <cstddef>

#define TT 64  // timesteps

#define RFL(x) __builtin_amdgcn_readfirstlane(x)

// ---------------- CUBA LIF step helpers ----------------
__device__ __forceinline__ void scanc(float& c, float& v, float& z) {
    c = fmaf(0.7f, c, z);
    v = fmaf(0.75f, v, c);
    float s = (v >= 1.0f) ? 1.0f : 0.0f;
    v = (v >= 1.0f) ? 0.0f : v;
    z = s;
}
__device__ __forceinline__ void scan4(float& c, float& v, float4& a) {
    scanc(c, v, a.x); scanc(c, v, a.y); scanc(c, v, a.z); scanc(c, v, a.w);
}

// ---------------- weight_norm (per output channel) --------------------------
template <bool TR>
__global__ __launch_bounds__(256) void wnorm(const float* __restrict__ v,
                                             const float* __restrict__ g,
                                             float* __restrict__ w, int O, int K,
                                             int LD) {
    __shared__ float red[256];
    const int o = blockIdx.x;
    float s = 0.f;
    for (int k = threadIdx.x; k < K; k += 256) {
        float x = v[(size_t)o * K + k];
        s += x * x;
    }
    red[threadIdx.x] = s;
    __syncthreads();
    for (int off = 128; off > 0; off >>= 1) {
        if (threadIdx.x < off) red[threadIdx.x] += red[threadIdx.x + off];
        __syncthreads();
    }
    const float scale = g[o] / sqrtf(red[0]);
    for (int k = threadIdx.x; k < K; k += 256) {
        float val = scale * v[(size_t)o * K + k];
        if (TR) w[(size_t)k * LD + o] = val;
        else    w[(size_t)o * K + k] = val;
    }
}

// ---------------- conv1 (2->8, 128x128 -> 32x32) fused with CUBA -----------
// All wave-uniform coords pinned to SGPRs: weight loads become scalar (s_load)
// and the 50-tap register buffer persists (VMEM freed for activations).
__global__ __launch_bounds__(256) void conv1_cuba(const float* __restrict__ x,
                                                  const float* __restrict__ w1T,
                                                  float* __restrict__ s1) {
    __shared__ float lds[4][8][68];
    const int wid = RFL(threadIdx.x >> 6), t = threadIdx.x & 63;
    const int task = RFL(blockIdx.x) * 4 + wid;  // 0..16383
    const int spi = task & 1023, b = task >> 10;
    const int oy = spi >> 5, ox = spi & 31;

    float a0=0,a1=0,a2=0,a3=0,a4=0,a5=0,a6=0,a7=0;
    const float* xb = x + (size_t)b * 2 * 128 * 128 * TT + t;

    if (oy >= 1 && ox >= 1) {
        const float* xq = xb + ((size_t)((oy * 4 - 1) * 128 + ox * 4 - 1)) * TT;
        float xv[50];
#pragma unroll
        for (int ci = 0; ci < 2; ci++)
#pragma unroll
            for (int ky = 0; ky < 5; ky++)
#pragma unroll
                for (int kx = 0; kx < 5; kx++)
                    xv[ci * 25 + ky * 5 + kx] =
                        xq[((size_t)(ci * 16384 + ky * 128 + kx)) * TT];
#pragma unroll
        for (int k = 0; k < 50; k++) {
            const float4* wp = (const float4*)(w1T + k * 8);
            const float4 wA = wp[0], wB = wp[1];
            const float xvk = xv[k];
            a0 = fmaf(wA.x, xvk, a0); a1 = fmaf(wA.y, xvk, a1);
            a2 = fmaf(wA.z, xvk, a2); a3 = fmaf(wA.w, xvk, a3);
            a4 = fmaf(wB.x, xvk, a4); a5 = fmaf(wB.y, xvk, a5);
            a6 = fmaf(wB.z, xvk, a6); a7 = fmaf(wB.w, xvk, a7);
        }
    } else {
        for (int ci = 0; ci < 2; ci++) {
#pragma unroll
            for (int ky = 0; ky < 5; ky++) {
                const int iy = oy * 4 + ky - 1;
                if (iy < 0 || iy >= 128) continue;
#pragma unroll
                for (int kx = 0; kx < 5; kx++) {
                    const int ix = ox * 4 + kx - 1;
                    if (ix < 0 || ix >= 128) continue;
                    const float xvk = xb[((size_t)((ci * 128 + iy) * 128 + ix)) * TT];
                    const float4* wp = (const float4*)(w1T + (ci * 25 + ky * 5 + kx) * 8);
                    const float4 wA = wp[0], wB = wp[1];
                    a0 = fmaf(wA.x, xvk, a0); a1 = fmaf(wA.y, xvk, a1);
                    a2 = fmaf(wA.z, xvk, a2); a3 = fmaf(wA.w, xvk, a3);
                    a4 = fmaf(wB.x, xvk, a4); a5 = fmaf(wB.y, xvk, a5);
                    a6 = fmaf(wB.z, xvk, a6); a7 = fmaf(wB.w, xvk, a7);
                }
            }
        }
    }
    lds[wid][0][t] = a0; lds[wid][1][t] = a1; lds[wid][2][t] = a2; lds[wid][3][t] = a3;
    lds[wid][4][t] = a4; lds[wid][5][t] = a5; lds[wid][6][t] = a6; lds[wid][7][t] = a7;
    __syncthreads();
    if (t < 8) {
        const int ch = t;
        float4 r[16];
#pragma unroll
        for (int j = 0; j < 16; j++) r[j] = *(const float4*)&lds[wid][ch][j * 4];
        float c = 0.f, v = 0.f;
#pragma unroll
        for (int j = 0; j < 16; j++) scan4(c, v, r[j]);
        float4* op = (float4*)(s1 + (((size_t)b * 8 + ch) * 1024 + spi) * TT);
#pragma unroll
        for (int j = 0; j < 16; j++) op[j] = r[j];
    }
}

// ---------------- conv2 z (8->32, 32x32 -> 8x8), t-parallel, 16 o/wave -----
// og/spi/b pinned to SGPRs -> the 800 wave-uniform weight loads become s_load
// on the scalar pipe; VMEM carries only the 200 coalesced activation loads.
__global__ __launch_bounds__(256) void conv2_z(const float* __restrict__ s1,
                                               const float* __restrict__ w2T,
                                               float* __restrict__ z2) {
    const int wid = RFL(threadIdx.x >> 6), t = threadIdx.x & 63;
    const int task = RFL(blockIdx.x) * 4 + wid;  // 0..2047
    const int og = task & 1;
    const int spi = (task >> 1) & 63;
    const int b = task >> 7;
    const int oy = spi >> 3, ox = spi & 7;

    float a[16];
#pragma unroll
    for (int j = 0; j < 16; j++) a[j] = 0.f;
    const float* xb = s1 + (size_t)b * 8 * 32 * 32 * TT + t;

    if (oy >= 1 && ox >= 1) {
        const float* xq = xb + ((size_t)((oy * 4 - 1) * 32 + ox * 4 - 1)) * TT;
        for (int cp = 0; cp < 4; cp++) {  // ci pairs: (0,1),(2,3),(4,5),(6,7)
            float xv[50];
#pragma unroll
            for (int cc = 0; cc < 2; cc++)
#pragma unroll
                for (int ky = 0; ky < 5; ky++)
#pragma unroll
                    for (int kx = 0; kx < 5; kx++)
                        xv[cc * 25 + ky * 5 + kx] =
                            xq[((size_t)(((cp * 2 + cc) * 1024) + ky * 32 + kx)) * TT];
#pragma unroll
            for (int k = 0; k < 50; k++) {
                const int row = (cp * 2 + (k >= 25 ? 1 : 0)) * 25 + (k >= 25 ? k - 25 : k);
                const float4* wp = (const float4*)(w2T + row * 32 + og * 16);
                const float4 w0 = wp[0], w1 = wp[1], w2 = wp[2], w3 = wp[3];
                const float xvk = xv[k];
                a[0]  = fmaf(w0.x, xvk, a[0]);  a[1]  = fmaf(w0.y, xvk, a[1]);
                a[2]  = fmaf(w0.z, xvk, a[2]);  a[3]  = fmaf(w0.w, xvk, a[3]);
                a[4]  = fmaf(w1.x, xvk, a[4]);  a[5]  = fmaf(w1.y, xvk, a[5]);
                a[6]  = fmaf(w1.z, xvk, a[6]);  a[7]  = fmaf(w1.w, xvk, a[7]);
                a[8]  = fmaf(w2.x, xvk, a[8]);  a[9]  = fmaf(w2.y, xvk, a[9]);
                a[10] = fmaf(w2.z, xvk, a[10]); a[11] = fmaf(w2.w, xvk, a[11]);
                a[12] = fmaf(w3.x, xvk, a[12]); a[13] = fmaf(w3.y, xvk, a[13]);
                a[14] = fmaf(w3.z, xvk, a[14]); a[15] = fmaf(w3.w, xvk, a[15]);
            }
        }
    } else {
        for (int ci = 0; ci < 8; ci++) {
#pragma unroll
            for (int ky = 0; ky < 5; ky++) {
                const int iy = oy * 4 + ky - 1;
                if (iy < 0 || iy >= 32) continue;
#pragma unroll
                for (int kx = 0; kx < 5; kx++) {
                    const int ix = ox * 4 + kx - 1;
                    if (ix < 0 || ix >= 32) continue;
                    const float xvk = xb[((size_t)((ci * 32 + iy) * 32 + ix)) * TT];
                    const float4* wp =
                        (const float4*)(w2T + (ci * 25 + ky * 5 + kx) * 32 + og * 16);
                    const float4 w0 = wp[0], w1 = wp[1], w2 = wp[2], w3 = wp[3];
                    a[0]  = fmaf(w0.x, xvk, a[0]);  a[1]  = fmaf(w0.y, xvk, a[1]);
                    a[2]  = fmaf(w0.z, xvk, a[2]);  a[3]  = fmaf(w0.w, xvk, a[3]);
                    a[4]  = fmaf(w1.x, xvk, a[4]);  a[5]  = fmaf(w1.y, xvk, a[5]);
                    a[6]  = fmaf(w1.z, xvk, a[6]);  a[7]  = fmaf(w1.w, xvk, a[7]);
                    a[8]  = fmaf(w2.x, xvk, a[8]);  a[9]  = fmaf(w2.y, xvk, a[9]);
                    a[10] = fmaf(w2.z, xvk, a[10]); a[11] = fmaf(w2.w, xvk, a[11]);
                    a[12] = fmaf(w3.x, xvk, a[12]); a[13] = fmaf(w3.y, xvk, a[13]);
                    a[14] = fmaf(w3.z, xvk, a[14]); a[15] = fmaf(w3.w, xvk, a[15]);
                }
            }
        }
    }
    float* zb = z2 + (((size_t)b * 32 + og * 16) * 64 + spi) * TT + t;
#pragma unroll
    for (int j = 0; j < 16; j++) zb[(size_t)j * 64 * TT] = a[j];
}

// ---------------- conv3 z (32->64, 8x8 -> 2x2), ci-split + batched taps -----
template <int OY, int OX>
__device__ __forceinline__ void conv3_acc(const float* __restrict__ xb,
                                          const float* __restrict__ wTo,
                                          int wid, float* __restrict__ acc) {
    constexpr int KY0 = (OY == 0) ? 1 : 0;
    constexpr int KX0 = (OX == 0) ? 1 : 0;
    constexpr int NKY = 5 - KY0;
    constexpr int NKX = 5 - KX0;
    for (int c8 = 0; c8 < 8; c8++) {
        const int ci = wid * 8 + c8;
        float xv[NKY * NKX];
#pragma unroll
        for (int ky = KY0; ky < 5; ky++) {
#pragma unroll
            for (int kx = KX0; kx < 5; kx++) {
                const int iy = OY * 4 + ky - 1;
                const int ix = OX * 4 + kx - 1;
                xv[(ky - KY0) * NKX + (kx - KX0)] =
                    xb[((size_t)((ci * 8 + iy) * 8 + ix)) * TT];
            }
        }
#pragma unroll
        for (int ky = KY0; ky < 5; ky++) {
#pragma unroll
            for (int kx = KX0; kx < 5; kx++) {
                const float xvk = xv[(ky - KY0) * NKX + (kx - KX0)];
                const float4* wp = (const float4*)(wTo + (ci * 25 + ky * 5 + kx) * 64);
                const float4 wA = wp[0], wB = wp[1];
                acc[0] = fmaf(wA.x, xvk, acc[0]); acc[1] = fmaf(wA.y, xvk, acc[1]);
                acc[2] = fmaf(wA.z, xvk, acc[2]); acc[3] = fmaf(wA.w, xvk, acc[3]);
                acc[4] = fmaf(wB.x, xvk, acc[4]); acc[5] = fmaf(wB.y, xvk, acc[5]);
                acc[6] = fmaf(wB.z, xvk, acc[6]); acc[7] = fmaf(wB.w, xvk, acc[7]);
            }
        }
    }
}

__global__ __launch_bounds__(256) void conv3_z(const float* __restrict__ s2,
                                               const float* __restrict__ wT,
                                               float* __restrict__ z3) {
    __shared__ float red[4][8][64];
    const int wid = RFL(threadIdx.x >> 6), t = threadIdx.x & 63;
    const int og = RFL(blockIdx.x) & 7;
    const int spi = (RFL(blockIdx.x) >> 3) & 3;
    const int b = RFL(blockIdx.x) >> 5;

    float acc[8];
#pragma unroll
    for (int j = 0; j < 8; j++) acc[j] = 0.f;
    const float* xb = s2 + (size_t)b * 32 * 8 * 8 * TT + t;
    const float* wTo = wT + og * 8;

    switch (spi) {
        case 0: conv3_acc<0, 0>(xb, wTo, wid, acc); break;
        case 1: conv3_acc<0, 1>(xb, wTo, wid, acc); break;
        case 2: conv3_acc<1, 0>(xb, wTo, wid, acc); break;
        default: conv3_acc<1, 1>(xb, wTo, wid, acc); break;
    }
#pragma unroll
    for (int j = 0; j < 8; j++) red[wid][j][t] = acc[j];
    __syncthreads();
    if (wid == 0) {
        float* zb = z3 + ((size_t)b * 256 + (size_t)og * 32 + spi) * TT + t;
#pragma unroll
        for (int j = 0; j < 8; j++) {
            const float s = ((red[0][j][t] + red[1][j][t]) + red[2][j][t]) + red[3][j][t];
            zb[(size_t)j * 4 * TT] = s;
        }
    }
}

// ---------------- generic de-fused CUBA scan: z (N,64) -> spikes (N,64) -----
__global__ __launch_bounds__(256) void scan_s(const float* __restrict__ z,
                                              float* __restrict__ s, int N) {
    const int n = blockIdx.x * 256 + threadIdx.x;
    if (n >= N) return;
    const float4* zp = (const float4*)(z + (size_t)n * TT);
    float4* sp = (float4*)(s + (size_t)n * TT);
    float c = 0.f, v = 0.f;
    for (int tc = 0; tc < 4; tc++) {
        float4 a0 = zp[tc * 4 + 0], a1 = zp[tc * 4 + 1];
        float4 a2 = zp[tc * 4 + 2], a3 = zp[tc * 4 + 3];
        scan4(c, v, a0); scan4(c, v, a1); scan4(c, v, a2); scan4(c, v, a3);
        sp[tc * 4 + 0] = a0; sp[tc * 4 + 1] = a1;
        sp[tc * 4 + 2] = a2; sp[tc * 4 + 3] = a3;
    }
}

// ---------------- dense1 z (256 -> 2056), 8 o/wave, scalar weight loads -----
__global__ __launch_bounds__(256) void dense1_z(const float* __restrict__ s3,
                                                const float* __restrict__ w,
                                                float* __restrict__ zd) {
    const int wid = threadIdx.x >> 6, t = threadIdx.x & 63;
    const int task = blockIdx.x * 4 + wid;  // 0..4111  (16 b x 257 og)
    const int bq = task / 257;
    const int ogq = task - bq * 257;
    const int b = RFL(bq);
    const int o0 = RFL(ogq * 8);

    float a0=0,a1=0,a2=0,a3=0,a4=0,a5=0,a6=0,a7=0;
    const float* ab = s3 + (size_t)b * 256 * TT + t;
    const float* r0 = w + (size_t)(o0 + 0) * 256;
    const float* r1 = w + (size_t)(o0 + 1) * 256;
    const float* r2 = w + (size_t)(o0 + 2) * 256;
    const float* r3 = w + (size_t)(o0 + 3) * 256;
    const float* r4 = w + (size_t)(o0 + 4) * 256;
    const float* r5 = w + (size_t)(o0 + 5) * 256;
    const float* r6 = w + (size_t)(o0 + 6) * 256;
    const float* r7 = w + (size_t)(o0 + 7) * 256;

#pragma unroll 2
    for (int i = 0; i < 256; i += 4) {
        const float av0 = ab[(size_t)(i + 0) * TT];
        const float av1 = ab[(size_t)(i + 1) * TT];
        const float av2 = ab[(size_t)(i + 2) * TT];
        const float av3 = ab[(size_t)(i + 3) * TT];
        const float4 q0 = *(const float4*)(r0 + i);
        const float4 q1 = *(const float4*)(r1 + i);
        const float4 q2 = *(const float4*)(r2 + i);
        const float4 q3 = *(const float4*)(r3 + i);
        const float4 q4 = *(const float4*)(r4 + i);
        const float4 q5 = *(const float4*)(r5 + i);
        const float4 q6 = *(const float4*)(r6 + i);
        const float4 q7 = *(const float4*)(r7 + i);
        a0 = fmaf(q0.x, av0, a0); a1 = fmaf(q1.x, av0, a1);
        a2 = fmaf(q2.x, av0, a2); a3 = fmaf(q3.x, av0, a3);
        a4 = fmaf(q4.x, av0, a4); a5 = fmaf(q5.x, av0, a5);
        a6 = fmaf(q6.x, av0, a6); a7 = fmaf(q7.x, av0, a7);
        a0 = fmaf(q0.y, av1, a0); a1 = fmaf(q1.y, av1, a1);
        a2 = fmaf(q2.y, av1, a2); a3 = fmaf(q3.y, av1, a3);
        a4 = fmaf(q4.y, av1, a4); a5 = fmaf(q5.y, av1, a5);
        a6 = fmaf(q6.y, av1, a6); a7 = fmaf(q7.y, av1, a7);
        a0 = fmaf(q0.z, av2, a0); a1 = fmaf(q1.z, av2, a1);
        a2 = fmaf(q2.z, av2, a2); a3 = fmaf(q3.z, av2, a3);
        a4 = fmaf(q4.z, av2, a4); a5 = fmaf(q5.z, av2, a5);
        a6 = fmaf(q6.z, av2, a6); a7 = fmaf(q7.z, av2, a7);
        a0 = fmaf(q0.w, av3, a0); a1 = fmaf(q1.w, av3, a1);
        a2 = fmaf(q2.w, av3, a2); a3 = fmaf(q3.w, av3, a3);
        a4 = fmaf(q4.w, av3, a4); a5 = fmaf(q5.w, av3, a5);
        a6 = fmaf(q6.w, av3, a6); a7 = fmaf(q7.w, av3, a7);
    }
    float* zb = zd + ((size_t)b * 2056 + o0) * TT + t;
    zb[0 * TT] = a0; zb[1 * TT] = a1; zb[2 * TT] = a2; zb[3 * TT] = a3;
    zb[4 * (size_t)TT] = a4; zb[5 * (size_t)TT] = a5;
    zb[6 * (size_t)TT] = a6; zb[7 * (size_t)TT] = a7;
}

// ---------------- dense2 stage 1: split-K partial sums ----------------------
__global__ __launch_bounds__(256) void dense2_part(const float* __restrict__ s4,
                                                   const float* __restrict__ wP,
                                                   float* __restrict__ z4p) {
    __shared__ float red[4][11][64];
    const int sp = blockIdx.x, b = blockIdx.y;
    const int w = threadIdx.x >> 6, t = threadIdx.x & 63;
    const int i0 = sp * 257, iend = i0 + 257;  // 2056 = 8*257
    const float* src = s4 + (size_t)b * 2056 * TT + t;

    float acc[11];
#pragma unroll
    for (int j = 0; j < 11; j++) acc[j] = 0.f;

    for (int i = i0 + w; i < iend; i += 4) {
        const float xv = src[(size_t)i * TT];
        const float4* wp = (const float4*)(wP + (size_t)i * 12);
        const float4 w0 = wp[0], w1 = wp[1], w2 = wp[2];
        acc[0]  = fmaf(w0.x, xv, acc[0]);  acc[1]  = fmaf(w0.y, xv, acc[1]);
        acc[2]  = fmaf(w0.z, xv, acc[2]);  acc[3]  = fmaf(w0.w, xv, acc[3]);
        acc[4]  = fmaf(w1.x, xv, acc[4]);  acc[5]  = fmaf(w1.y, xv, acc[5]);
        acc[6]  = fmaf(w1.z, xv, acc[6]);  acc[7]  = fmaf(w1.w, xv, acc[7]);
        acc[8]  = fmaf(w2.x, xv, acc[8]);  acc[9]  = fmaf(w2.y, xv, acc[9]);
        acc[10] = fmaf(w2.z, xv, acc[10]);
    }
#pragma unroll
    for (int j = 0; j < 11; j++) red[w][j][t] = acc[j];
    __syncthreads();
    if (w == 0) {
#pragma unroll
        for (int j = 0; j < 11; j++) {
            const float s = red[0][j][t] + red[1][j][t] + red[2][j][t] + red[3][j][t];
            z4p[(((size_t)b * 8 + sp) * 11 + j) * TT + t] = s;
        }
    }
}

// ---------------- dense2 stage 2: fixed-order reduce + final CUBA scan ------
__global__ __launch_bounds__(256) void dense2_scan(const float* __restrict__ z4p,
                                                   float* __restrict__ out) {
    __shared__ float z[11][64];
    const int b = blockIdx.x;
    for (int idx = threadIdx.x; idx < 11 * 64; idx += 256) {
        const int o = idx >> 6, t = idx & 63;
        float s = 0.f;
#pragma unroll
        for (int sp = 0; sp < 8; sp++)
            s += z4p[(((size_t)b * 8 + sp) * 11 + o) * TT + t];
        z[o][t] = s;
    }
    __syncthreads();
    if (threadIdx.x < 11) {
        const int o = threadIdx.x;
        float c = 0.f, v = 0.f;
        float* op = out + ((size_t)b * 11 + o) * TT;
#pragma unroll
        for (int t = 0; t < TT; t++) {
            float zz = z[o][t];
            scanc(c, v, zz);
            op[t] = zz;
        }
    }
}

extern "C" void kernel_launch(void* const* d_in, const int* in_sizes, int n_in,
                              void* d_out, int out_size, void* d_ws, size_t ws_size,
                              hipStream_t stream) {
    const float* x   = (const float*)d_in[0];
    const float* c1v = (const float*)d_in[1];  const float* c1g = (const float*)d_in[2];
    const float* c2v = (const float*)d_in[3];  const float* c2g = (const float*)d_in[4];
    const float* c3v = (const float*)d_in[5];  const float* c3g = (const float*)d_in[6];
    const float* d1v = (const float*)d_in[7];  const float* d1g = (const float*)d_in[8];
    const float* d2v = (const float*)d_in[9];  const float* d2g = (const float*)d_in[10];

    float* ws = (float*)d_ws;
    // weight region
    float* w1T  = ws + 0;        // (50,8)     = 400
    float* w2T  = ws + 400;      // (200,32)   = 6400
    float* w3T  = ws + 6800;     // (800,64)   = 51200
    float* wd1  = ws + 58000;    // (2056,256) original layout = 526336
    float* wd2P = ws + 584336;   // (2056,12) padded = 24672
    // region A (8,388,608 floats) and region B (4,194,304 floats), multiplexed
    float* A = ws + 609008;
    float* B = A + 8388608;
    float* s1  = A;              // conv1 spikes (b,8,32,32,t)
    float* s3  = A;              // dense-in spikes (b,256,t)    [after s1 dead]
    float* s4  = A + 262144;     // dense1 spikes (b,2056,t)
    float* z2  = B;              // conv2 pre-act (b,32,64,t)
    float* s2  = B + 2097152;    // conv2 spikes
    float* z3  = B;              // conv3 pre-act (b,256,t)      [after z2 dead]
    float* zd1 = B;              // dense1 pre-act (b,2056,t)    [after z3,s2 dead]
    float* z4p = B;              // dense2 partials (b,8,11,t)   [after zd1 dead]
    (void)ws_size; (void)in_sizes; (void)n_in; (void)out_size;

    // normalized weights
    wnorm<true> <<<dim3(8),    dim3(256), 0, stream>>>(c1v, c1g, w1T, 8, 50, 8);
    wnorm<true> <<<dim3(32),   dim3(256), 0, stream>>>(c2v, c2g, w2T, 32, 200, 32);
    wnorm<true> <<<dim3(64),   dim3(256), 0, stream>>>(c3v, c3g, w3T, 64, 800, 64);
    wnorm<false><<<dim3(2056), dim3(256), 0, stream>>>(d1v, d1g, wd1, 2056, 256, 256);
    wnorm<true> <<<dim3(11),   dim3(256), 0, stream>>>(d2v, d2g, wd2P, 11, 2056, 12);

    // pipeline
    conv1_cuba <<<dim3(4096), dim3(256), 0, stream>>>(x, w1T, s1);
    conv2_z    <<<dim3(512),  dim3(256), 0, stream>>>(s1, w2T, z2);
    scan_s     <<<dim3(128),  dim3(256), 0, stream>>>(z2, s2, 32768);
    conv3_z    <<<dim3(512),  dim3(256), 0, stream>>>(s2, w3T, z3);
    scan_s     <<<dim3(16),   dim3(256), 0, stream>>>(z3, s3, 4096);
    dense1_z   <<<dim3(1028), dim3(256), 0, stream>>>(s3, wd1, zd1);
    scan_s     <<<dim3(129),  dim3(256), 0, stream>>>(zd1, s4, 32896);
    dense2_part<<<dim3(8, 16), dim3(256), 0, stream>>>(s4, wd2P, z4p);
    dense2_scan<<<dim3(16),   dim3(256), 0, stream>>>(z4p, (float*)d_out);
}

// Round 9
// 163.359 us; speedup vs baseline: 8.3570x; 1.2091x over previous
//
#include <hip/hip_runtime.h>
#include <cstddef>

#define TT 64  // timesteps

#define RFL(x) __builtin_amdgcn_readfirstlane(x)

// ---------------- CUBA LIF step helpers ----------------
__device__ __forceinline__ void scanc(float& c, float& v, float& z) {
    c = fmaf(0.7f, c, z);
    v = fmaf(0.75f, v, c);
    float s = (v >= 1.0f) ? 1.0f : 0.0f;
    v = (v >= 1.0f) ? 0.0f : v;
    z = s;
}
__device__ __forceinline__ void scan4(float& c, float& v, float4& a) {
    scanc(c, v, a.x); scanc(c, v, a.y); scanc(c, v, a.z); scanc(c, v, a.w);
}

// ---------------- all weight_norms in ONE dispatch --------------------------
// Segments: conv1(8,K=50,TR ld8) conv2(32,K=200,TR ld32) conv3(64,K=800,TR ld64)
// dense1(2056,K=256,no-TR) dense2(11,K=2056,TR ld12). Same per-o reduction as
// the original wnorm -> bit-identical weights.
__global__ __launch_bounds__(256) void wnorm_all(
    const float* __restrict__ c1v, const float* __restrict__ c1g, float* __restrict__ w1T,
    const float* __restrict__ c2v, const float* __restrict__ c2g, float* __restrict__ w2T,
    const float* __restrict__ c3v, const float* __restrict__ c3g, float* __restrict__ w3T,
    const float* __restrict__ d1v, const float* __restrict__ d1g, float* __restrict__ wd1,
    const float* __restrict__ d2v, const float* __restrict__ d2g, float* __restrict__ wd2P) {
    __shared__ float red[256];
    const int bid = blockIdx.x;
    const float *v, *g; float* w; int o, K, LD; bool tr;
    if (bid < 8)         { v = c1v; g = c1g; w = w1T;  o = bid;        K = 50;   LD = 8;  tr = true;  }
    else if (bid < 40)   { v = c2v; g = c2g; w = w2T;  o = bid - 8;    K = 200;  LD = 32; tr = true;  }
    else if (bid < 104)  { v = c3v; g = c3g; w = w3T;  o = bid - 40;   K = 800;  LD = 64; tr = true;  }
    else if (bid < 2160) { v = d1v; g = d1g; w = wd1;  o = bid - 104;  K = 256;  LD = 0;  tr = false; }
    else                 { v = d2v; g = d2g; w = wd2P; o = bid - 2160; K = 2056; LD = 12; tr = true;  }

    float s = 0.f;
    for (int k = threadIdx.x; k < K; k += 256) {
        float x = v[(size_t)o * K + k];
        s += x * x;
    }
    red[threadIdx.x] = s;
    __syncthreads();
    for (int off = 128; off > 0; off >>= 1) {
        if (threadIdx.x < off) red[threadIdx.x] += red[threadIdx.x + off];
        __syncthreads();
    }
    const float scale = g[o] / sqrtf(red[0]);
    for (int k = threadIdx.x; k < K; k += 256) {
        float val = scale * v[(size_t)o * K + k];
        if (tr) w[(size_t)k * LD + o] = val;
        else    w[(size_t)o * K + k] = val;
    }
}

// ---------------- conv1 (2->8) fused with CUBA ------------------------------
__global__ __launch_bounds__(256) void conv1_cuba(const float* __restrict__ x,
                                                  const float* __restrict__ w1T,
                                                  float* __restrict__ s1) {
    __shared__ float lds[4][8][68];
    const int wid = RFL(threadIdx.x >> 6), t = threadIdx.x & 63;
    const int task = RFL(blockIdx.x) * 4 + wid;  // 0..16383
    const int spi = task & 1023, b = task >> 10;
    const int oy = spi >> 5, ox = spi & 31;

    float a0=0,a1=0,a2=0,a3=0,a4=0,a5=0,a6=0,a7=0;
    const float* xb = x + (size_t)b * 2 * 128 * 128 * TT + t;

    if (oy >= 1 && ox >= 1) {
        const float* xq = xb + ((size_t)((oy * 4 - 1) * 128 + ox * 4 - 1)) * TT;
        float xv[50];
#pragma unroll
        for (int ci = 0; ci < 2; ci++)
#pragma unroll
            for (int ky = 0; ky < 5; ky++)
#pragma unroll
                for (int kx = 0; kx < 5; kx++)
                    xv[ci * 25 + ky * 5 + kx] =
                        xq[((size_t)(ci * 16384 + ky * 128 + kx)) * TT];
#pragma unroll
        for (int k = 0; k < 50; k++) {
            const float4* wp = (const float4*)(w1T + k * 8);
            const float4 wA = wp[0], wB = wp[1];
            const float xvk = xv[k];
            a0 = fmaf(wA.x, xvk, a0); a1 = fmaf(wA.y, xvk, a1);
            a2 = fmaf(wA.z, xvk, a2); a3 = fmaf(wA.w, xvk, a3);
            a4 = fmaf(wB.x, xvk, a4); a5 = fmaf(wB.y, xvk, a5);
            a6 = fmaf(wB.z, xvk, a6); a7 = fmaf(wB.w, xvk, a7);
        }
    } else {
        for (int ci = 0; ci < 2; ci++) {
#pragma unroll
            for (int ky = 0; ky < 5; ky++) {
                const int iy = oy * 4 + ky - 1;
                if (iy < 0 || iy >= 128) continue;
#pragma unroll
                for (int kx = 0; kx < 5; kx++) {
                    const int ix = ox * 4 + kx - 1;
                    if (ix < 0 || ix >= 128) continue;
                    const float xvk = xb[((size_t)((ci * 128 + iy) * 128 + ix)) * TT];
                    const float4* wp = (const float4*)(w1T + (ci * 25 + ky * 5 + kx) * 8);
                    const float4 wA = wp[0], wB = wp[1];
                    a0 = fmaf(wA.x, xvk, a0); a1 = fmaf(wA.y, xvk, a1);
                    a2 = fmaf(wA.z, xvk, a2); a3 = fmaf(wA.w, xvk, a3);
                    a4 = fmaf(wB.x, xvk, a4); a5 = fmaf(wB.y, xvk, a5);
                    a6 = fmaf(wB.z, xvk, a6); a7 = fmaf(wB.w, xvk, a7);
                }
            }
        }
    }
    lds[wid][0][t] = a0; lds[wid][1][t] = a1; lds[wid][2][t] = a2; lds[wid][3][t] = a3;
    lds[wid][4][t] = a4; lds[wid][5][t] = a5; lds[wid][6][t] = a6; lds[wid][7][t] = a7;
    __syncthreads();
    if (t < 8) {
        const float* row = &lds[wid][t][0];
        float4* op = (float4*)(s1 + (((size_t)b * 8 + t) * 1024 + spi) * TT);
        float c = 0.f, v = 0.f;
        for (int tc = 0; tc < 4; tc++) {
            float4 r0 = *(const float4*)&row[tc * 16 + 0];
            float4 r1 = *(const float4*)&row[tc * 16 + 4];
            float4 r2 = *(const float4*)&row[tc * 16 + 8];
            float4 r3 = *(const float4*)&row[tc * 16 + 12];
            scan4(c, v, r0); scan4(c, v, r1); scan4(c, v, r2); scan4(c, v, r3);
            op[tc * 4 + 0] = r0; op[tc * 4 + 1] = r1;
            op[tc * 4 + 2] = r2; op[tc * 4 + 3] = r3;
        }
    }
}

// ---------------- conv2 (8->32) fused with CUBA -----------------------------
// Same z computation as conv2_z; scan fused via per-wave LDS transpose
// (bit-identical z -> bit-identical spikes; z2 buffer eliminated).
__global__ __launch_bounds__(256) void conv2_cuba(const float* __restrict__ s1,
                                                  const float* __restrict__ w2T,
                                                  float* __restrict__ s2) {
    __shared__ float lds[4][16][68];
    const int wid = RFL(threadIdx.x >> 6), t = threadIdx.x & 63;
    const int task = RFL(blockIdx.x) * 4 + wid;  // 0..2047
    const int og = task & 1;
    const int spi = (task >> 1) & 63;
    const int b = task >> 7;
    const int oy = spi >> 3, ox = spi & 7;

    float a[16];
#pragma unroll
    for (int j = 0; j < 16; j++) a[j] = 0.f;
    const float* xb = s1 + (size_t)b * 8 * 32 * 32 * TT + t;

    if (oy >= 1 && ox >= 1) {
        const float* xq = xb + ((size_t)((oy * 4 - 1) * 32 + ox * 4 - 1)) * TT;
        for (int cp = 0; cp < 4; cp++) {  // ci pairs
            float xv[50];
#pragma unroll
            for (int cc = 0; cc < 2; cc++)
#pragma unroll
                for (int ky = 0; ky < 5; ky++)
#pragma unroll
                    for (int kx = 0; kx < 5; kx++)
                        xv[cc * 25 + ky * 5 + kx] =
                            xq[((size_t)(((cp * 2 + cc) * 1024) + ky * 32 + kx)) * TT];
#pragma unroll
            for (int k = 0; k < 50; k++) {
                const int row = (cp * 2 + (k >= 25 ? 1 : 0)) * 25 + (k >= 25 ? k - 25 : k);
                const float4* wp = (const float4*)(w2T + row * 32 + og * 16);
                const float4 w0 = wp[0], w1 = wp[1], w2 = wp[2], w3 = wp[3];
                const float xvk = xv[k];
                a[0]  = fmaf(w0.x, xvk, a[0]);  a[1]  = fmaf(w0.y, xvk, a[1]);
                a[2]  = fmaf(w0.z, xvk, a[2]);  a[3]  = fmaf(w0.w, xvk, a[3]);
                a[4]  = fmaf(w1.x, xvk, a[4]);  a[5]  = fmaf(w1.y, xvk, a[5]);
                a[6]  = fmaf(w1.z, xvk, a[6]);  a[7]  = fmaf(w1.w, xvk, a[7]);
                a[8]  = fmaf(w2.x, xvk, a[8]);  a[9]  = fmaf(w2.y, xvk, a[9]);
                a[10] = fmaf(w2.z, xvk, a[10]); a[11] = fmaf(w2.w, xvk, a[11]);
                a[12] = fmaf(w3.x, xvk, a[12]); a[13] = fmaf(w3.y, xvk, a[13]);
                a[14] = fmaf(w3.z, xvk, a[14]); a[15] = fmaf(w3.w, xvk, a[15]);
            }
        }
    } else {
        for (int ci = 0; ci < 8; ci++) {
#pragma unroll
            for (int ky = 0; ky < 5; ky++) {
                const int iy = oy * 4 + ky - 1;
                if (iy < 0 || iy >= 32) continue;
#pragma unroll
                for (int kx = 0; kx < 5; kx++) {
                    const int ix = ox * 4 + kx - 1;
                    if (ix < 0 || ix >= 32) continue;
                    const float xvk = xb[((size_t)((ci * 32 + iy) * 32 + ix)) * TT];
                    const float4* wp =
                        (const float4*)(w2T + (ci * 25 + ky * 5 + kx) * 32 + og * 16);
                    const float4 w0 = wp[0], w1 = wp[1], w2 = wp[2], w3 = wp[3];
                    a[0]  = fmaf(w0.x, xvk, a[0]);  a[1]  = fmaf(w0.y, xvk, a[1]);
                    a[2]  = fmaf(w0.z, xvk, a[2]);  a[3]  = fmaf(w0.w, xvk, a[3]);
                    a[4]  = fmaf(w1.x, xvk, a[4]);  a[5]  = fmaf(w1.y, xvk, a[5]);
                    a[6]  = fmaf(w1.z, xvk, a[6]);  a[7]  = fmaf(w1.w, xvk, a[7]);
                    a[8]  = fmaf(w2.x, xvk, a[8]);  a[9]  = fmaf(w2.y, xvk, a[9]);
                    a[10] = fmaf(w2.z, xvk, a[10]); a[11] = fmaf(w2.w, xvk, a[11]);
                    a[12] = fmaf(w3.x, xvk, a[12]); a[13] = fmaf(w3.y, xvk, a[13]);
                    a[14] = fmaf(w3.z, xvk, a[14]); a[15] = fmaf(w3.w, xvk, a[15]);
                }
            }
        }
    }
#pragma unroll
    for (int j = 0; j < 16; j++) lds[wid][j][t] = a[j];
    __syncthreads();
    if (t < 16) {
        const float* row = &lds[wid][t][0];
        float4* op = (float4*)(s2 + (((size_t)b * 32 + og * 16 + t) * 64 + spi) * TT);
        float c = 0.f, v = 0.f;
        for (int tc = 0; tc < 4; tc++) {
            float4 r0 = *(const float4*)&row[tc * 16 + 0];
            float4 r1 = *(const float4*)&row[tc * 16 + 4];
            float4 r2 = *(const float4*)&row[tc * 16 + 8];
            float4 r3 = *(const float4*)&row[tc * 16 + 12];
            scan4(c, v, r0); scan4(c, v, r1); scan4(c, v, r2); scan4(c, v, r3);
            op[tc * 4 + 0] = r0; op[tc * 4 + 1] = r1;
            op[tc * 4 + 2] = r2; op[tc * 4 + 3] = r3;
        }
    }
}

// ---------------- conv3 (32->64) fused with CUBA ----------------------------
template <int OY, int OX>
__device__ __forceinline__ void conv3_acc(const float* __restrict__ xb,
                                          const float* __restrict__ wTo,
                                          int wid, float* __restrict__ acc) {
    constexpr int KY0 = (OY == 0) ? 1 : 0;
    constexpr int KX0 = (OX == 0) ? 1 : 0;
    constexpr int NKY = 5 - KY0;
    constexpr int NKX = 5 - KX0;
    for (int c8 = 0; c8 < 8; c8++) {
        const int ci = wid * 8 + c8;
        float xv[NKY * NKX];
#pragma unroll
        for (int ky = KY0; ky < 5; ky++) {
#pragma unroll
            for (int kx = KX0; kx < 5; kx++) {
                const int iy = OY * 4 + ky - 1;
                const int ix = OX * 4 + kx - 1;
                xv[(ky - KY0) * NKX + (kx - KX0)] =
                    xb[((size_t)((ci * 8 + iy) * 8 + ix)) * TT];
            }
        }
#pragma unroll
        for (int ky = KY0; ky < 5; ky++) {
#pragma unroll
            for (int kx = KX0; kx < 5; kx++) {
                const float xvk = xv[(ky - KY0) * NKX + (kx - KX0)];
                const float4* wp = (const float4*)(wTo + (ci * 25 + ky * 5 + kx) * 64);
                const float4 wA = wp[0], wB = wp[1];
                acc[0] = fmaf(wA.x, xvk, acc[0]); acc[1] = fmaf(wA.y, xvk, acc[1]);
                acc[2] = fmaf(wA.z, xvk, acc[2]); acc[3] = fmaf(wA.w, xvk, acc[3]);
                acc[4] = fmaf(wB.x, xvk, acc[4]); acc[5] = fmaf(wB.y, xvk, acc[5]);
                acc[6] = fmaf(wB.z, xvk, acc[6]); acc[7] = fmaf(wB.w, xvk, acc[7]);
            }
        }
    }
}

__global__ __launch_bounds__(256) void conv3_cuba(const float* __restrict__ s2,
                                                  const float* __restrict__ wT,
                                                  float* __restrict__ s3) {
    __shared__ float red[4][8][68];
    const int wid = RFL(threadIdx.x >> 6), t = threadIdx.x & 63;
    const int og = RFL(blockIdx.x) & 7;
    const int spi = (RFL(blockIdx.x) >> 3) & 3;
    const int b = RFL(blockIdx.x) >> 5;

    float acc[8];
#pragma unroll
    for (int j = 0; j < 8; j++) acc[j] = 0.f;
    const float* xb = s2 + (size_t)b * 32 * 8 * 8 * TT + t;
    const float* wTo = wT + og * 8;

    switch (spi) {
        case 0: conv3_acc<0, 0>(xb, wTo, wid, acc); break;
        case 1: conv3_acc<0, 1>(xb, wTo, wid, acc); break;
        case 2: conv3_acc<1, 0>(xb, wTo, wid, acc); break;
        default: conv3_acc<1, 1>(xb, wTo, wid, acc); break;
    }
#pragma unroll
    for (int j = 0; j < 8; j++) red[wid][j][t] = acc[j];
    __syncthreads();
    if (wid == 0) {
#pragma unroll
        for (int j = 0; j < 8; j++)
            red[0][j][t] = ((red[0][j][t] + red[1][j][t]) + red[2][j][t]) + red[3][j][t];
    }
    __syncthreads();
    if (threadIdx.x < 8) {
        const int j = threadIdx.x;
        const float* row = &red[0][j][0];
        // feature = og*32 + j*4 + spi  (matches previous z3 layout)
        float4* op = (float4*)(s3 + ((size_t)b * 256 + og * 32 + j * 4 + spi) * TT);
        float c = 0.f, v = 0.f;
        for (int tc = 0; tc < 4; tc++) {
            float4 r0 = *(const float4*)&row[tc * 16 + 0];
            float4 r1 = *(const float4*)&row[tc * 16 + 4];
            float4 r2 = *(const float4*)&row[tc * 16 + 8];
            float4 r3 = *(const float4*)&row[tc * 16 + 12];
            scan4(c, v, r0); scan4(c, v, r1); scan4(c, v, r2); scan4(c, v, r3);
            op[tc * 4 + 0] = r0; op[tc * 4 + 1] = r1;
            op[tc * 4 + 2] = r2; op[tc * 4 + 3] = r3;
        }
    }
}

// ---------------- dense1 (256 -> 2056) fused with CUBA ----------------------
__global__ __launch_bounds__(256) void dense1_cuba(const float* __restrict__ s3,
                                                   const float* __restrict__ w,
                                                   float* __restrict__ s4) {
    __shared__ float lds[4][8][68];
    const int wid = threadIdx.x >> 6, t = threadIdx.x & 63;
    const int task = blockIdx.x * 4 + wid;  // 0..4111  (16 b x 257 og)
    const int bq = task / 257;
    const int ogq = task - bq * 257;
    const int b = RFL(bq);
    const int o0 = RFL(ogq * 8);

    float a0=0,a1=0,a2=0,a3=0,a4=0,a5=0,a6=0,a7=0;
    const float* ab = s3 + (size_t)b * 256 * TT + t;
    const float* r0 = w + (size_t)(o0 + 0) * 256;
    const float* r1 = w + (size_t)(o0 + 1) * 256;
    const float* r2 = w + (size_t)(o0 + 2) * 256;
    const float* r3 = w + (size_t)(o0 + 3) * 256;
    const float* r4 = w + (size_t)(o0 + 4) * 256;
    const float* r5 = w + (size_t)(o0 + 5) * 256;
    const float* r6 = w + (size_t)(o0 + 6) * 256;
    const float* r7 = w + (size_t)(o0 + 7) * 256;

#pragma unroll 2
    for (int i = 0; i < 256; i += 4) {
        const float av0 = ab[(size_t)(i + 0) * TT];
        const float av1 = ab[(size_t)(i + 1) * TT];
        const float av2 = ab[(size_t)(i + 2) * TT];
        const float av3 = ab[(size_t)(i + 3) * TT];
        const float4 q0 = *(const float4*)(r0 + i);
        const float4 q1 = *(const float4*)(r1 + i);
        const float4 q2 = *(const float4*)(r2 + i);
        const float4 q3 = *(const float4*)(r3 + i);
        const float4 q4 = *(const float4*)(r4 + i);
        const float4 q5 = *(const float4*)(r5 + i);
        const float4 q6 = *(const float4*)(r6 + i);
        const float4 q7 = *(const float4*)(r7 + i);
        a0 = fmaf(q0.x, av0, a0); a1 = fmaf(q1.x, av0, a1);
        a2 = fmaf(q2.x, av0, a2); a3 = fmaf(q3.x, av0, a3);
        a4 = fmaf(q4.x, av0, a4); a5 = fmaf(q5.x, av0, a5);
        a6 = fmaf(q6.x, av0, a6); a7 = fmaf(q7.x, av0, a7);
        a0 = fmaf(q0.y, av1, a0); a1 = fmaf(q1.y, av1, a1);
        a2 = fmaf(q2.y, av1, a2); a3 = fmaf(q3.y, av1, a3);
        a4 = fmaf(q4.y, av1, a4); a5 = fmaf(q5.y, av1, a5);
        a6 = fmaf(q6.y, av1, a6); a7 = fmaf(q7.y, av1, a7);
        a0 = fmaf(q0.z, av2, a0); a1 = fmaf(q1.z, av2, a1);
        a2 = fmaf(q2.z, av2, a2); a3 = fmaf(q3.z, av2, a3);
        a4 = fmaf(q4.z, av2, a4); a5 = fmaf(q5.z, av2, a5);
        a6 = fmaf(q6.z, av2, a6); a7 = fmaf(q7.z, av2, a7);
        a0 = fmaf(q0.w, av3, a0); a1 = fmaf(q1.w, av3, a1);
        a2 = fmaf(q2.w, av3, a2); a3 = fmaf(q3.w, av3, a3);
        a4 = fmaf(q4.w, av3, a4); a5 = fmaf(q5.w, av3, a5);
        a6 = fmaf(q6.w, av3, a6); a7 = fmaf(q7.w, av3, a7);
    }
    lds[wid][0][t] = a0; lds[wid][1][t] = a1; lds[wid][2][t] = a2; lds[wid][3][t] = a3;
    lds[wid][4][t] = a4; lds[wid][5][t] = a5; lds[wid][6][t] = a6; lds[wid][7][t] = a7;
    __syncthreads();
    if (t < 8) {
        const float* row = &lds[wid][t][0];
        float4* op = (float4*)(s4 + ((size_t)b * 2056 + o0 + t) * TT);
        float c = 0.f, v = 0.f;
        for (int tc = 0; tc < 4; tc++) {
            float4 r0q = *(const float4*)&row[tc * 16 + 0];
            float4 r1q = *(const float4*)&row[tc * 16 + 4];
            float4 r2q = *(const float4*)&row[tc * 16 + 8];
            float4 r3q = *(const float4*)&row[tc * 16 + 12];
            scan4(c, v, r0q); scan4(c, v, r1q); scan4(c, v, r2q); scan4(c, v, r3q);
            op[tc * 4 + 0] = r0q; op[tc * 4 + 1] = r1q;
            op[tc * 4 + 2] = r2q; op[tc * 4 + 3] = r3q;
        }
    }
}

// ---------------- dense2 stage 1: split-K partial sums ----------------------
__global__ __launch_bounds__(256) void dense2_part(const float* __restrict__ s4,
                                                   const float* __restrict__ wP,
                                                   float* __restrict__ z4p) {
    __shared__ float red[4][11][64];
    const int sp = blockIdx.x, b = blockIdx.y;
    const int w = threadIdx.x >> 6, t = threadIdx.x & 63;
    const int i0 = sp * 257, iend = i0 + 257;  // 2056 = 8*257
    const float* src = s4 + (size_t)b * 2056 * TT + t;

    float acc[11];
#pragma unroll
    for (int j = 0; j < 11; j++) acc[j] = 0.f;

    for (int i = i0 + w; i < iend; i += 4) {
        const float xv = src[(size_t)i * TT];
        const float4* wp = (const float4*)(wP + (size_t)i * 12);
        const float4 w0 = wp[0], w1 = wp[1], w2 = wp[2];
        acc[0]  = fmaf(w0.x, xv, acc[0]);  acc[1]  = fmaf(w0.y, xv, acc[1]);
        acc[2]  = fmaf(w0.z, xv, acc[2]);  acc[3]  = fmaf(w0.w, xv, acc[3]);
        acc[4]  = fmaf(w1.x, xv, acc[4]);  acc[5]  = fmaf(w1.y, xv, acc[5]);
        acc[6]  = fmaf(w1.z, xv, acc[6]);  acc[7]  = fmaf(w1.w, xv, acc[7]);
        acc[8]  = fmaf(w2.x, xv, acc[8]);  acc[9]  = fmaf(w2.y, xv, acc[9]);
        acc[10] = fmaf(w2.z, xv, acc[10]);
    }
#pragma unroll
    for (int j = 0; j < 11; j++) red[w][j][t] = acc[j];
    __syncthreads();
    if (w == 0) {
#pragma unroll
        for (int j = 0; j < 11; j++) {
            const float s = red[0][j][t] + red[1][j][t] + red[2][j][t] + red[3][j][t];
            z4p[(((size_t)b * 8 + sp) * 11 + j) * TT + t] = s;
        }
    }
}

// ---------------- dense2 stage 2: fixed-order reduce + final CUBA scan ------
__global__ __launch_bounds__(256) void dense2_scan(const float* __restrict__ z4p,
                                                   float* __restrict__ out) {
    __shared__ float z[11][64];
    const int b = blockIdx.x;
    for (int idx = threadIdx.x; idx < 11 * 64; idx += 256) {
        const int o = idx >> 6, t = idx & 63;
        float s = 0.f;
#pragma unroll
        for (int sp = 0; sp < 8; sp++)
            s += z4p[(((size_t)b * 8 + sp) * 11 + o) * TT + t];
        z[o][t] = s;
    }
    __syncthreads();
    if (threadIdx.x < 11) {
        const int o = threadIdx.x;
        float c = 0.f, v = 0.f;
        float* op = out + ((size_t)b * 11 + o) * TT;
#pragma unroll
        for (int t = 0; t < TT; t++) {
            float zz = z[o][t];
            scanc(c, v, zz);
            op[t] = zz;
        }
    }
}

extern "C" void kernel_launch(void* const* d_in, const int* in_sizes, int n_in,
                              void* d_out, int out_size, void* d_ws, size_t ws_size,
                              hipStream_t stream) {
    const float* x   = (const float*)d_in[0];
    const float* c1v = (const float*)d_in[1];  const float* c1g = (const float*)d_in[2];
    const float* c2v = (const float*)d_in[3];  const float* c2g = (const float*)d_in[4];
    const float* c3v = (const float*)d_in[5];  const float* c3g = (const float*)d_in[6];
    const float* d1v = (const float*)d_in[7];  const float* d1g = (const float*)d_in[8];
    const float* d2v = (const float*)d_in[9];  const float* d2g = (const float*)d_in[10];

    float* ws = (float*)d_ws;
    // weight region
    float* w1T  = ws + 0;        // (50,8)     = 400
    float* w2T  = ws + 400;      // (200,32)   = 6400
    float* w3T  = ws + 6800;     // (800,64)   = 51200
    float* wd1  = ws + 58000;    // (2056,256) original layout = 526336
    float* wd2P = ws + 584336;   // (2056,12) padded = 24672
    // activation regions
    float* A = ws + 609008;
    float* B = A + 8388608;
    float* s1  = A;              // conv1 spikes (b,8,32,32,t)
    float* s3  = A;              // dense-in spikes (b,256,t)  [after s1 dead]
    float* s4  = A + 262144;     // dense1 spikes (b,2056,t)
    float* s2  = B;              // conv2 spikes (b,32,8,8,t)
    float* z4p = B + 2097152;    // dense2 partials (b,8,11,t)
    (void)ws_size; (void)in_sizes; (void)n_in; (void)out_size;

    // all weight norms in one dispatch
    wnorm_all<<<dim3(2171), dim3(256), 0, stream>>>(c1v, c1g, w1T, c2v, c2g, w2T,
                                                    c3v, c3g, w3T, d1v, d1g, wd1,
                                                    d2v, d2g, wd2P);

    // pipeline: 6 fused kernels
    conv1_cuba <<<dim3(4096), dim3(256), 0, stream>>>(x, w1T, s1);
    conv2_cuba <<<dim3(512),  dim3(256), 0, stream>>>(s1, w2T, s2);
    conv3_cuba <<<dim3(512),  dim3(256), 0, stream>>>(s2, w3T, s3);
    dense1_cuba<<<dim3(1028), dim3(256), 0, stream>>>(s3, wd1, s4);
    dense2_part<<<dim3(8, 16), dim3(256), 0, stream>>>(s4, wd2P, z4p);
    dense2_scan<<<dim3(16),   dim3(256), 0, stream>>>(z4p, (float*)d_out);
}